// Round 8
// baseline (1272.515 us; speedup 1.0000x reference)
//
#include <hip/hip_runtime.h>

typedef __bf16 bf16x8 __attribute__((ext_vector_type(8)));
typedef float f32x4 __attribute__((ext_vector_type(4)));
typedef unsigned short u16x8 __attribute__((ext_vector_type(8)));

#define LOG2E 1.4426950408889634f

__device__ __forceinline__ unsigned short f2bf(float f) {
  union { float f; unsigned u; } v; v.f = f;
  return (unsigned short)((v.u + 0x7fffu + ((v.u >> 16) & 1u)) >> 16);
}

__device__ __forceinline__ void gload16(const void* g, void* l) {
  __builtin_amdgcn_global_load_lds(
      (const __attribute__((address_space(1))) unsigned int*)g,
      (__attribute__((address_space(3))) unsigned int*)l, 16, 0, 0);
}

// ---------------- weight f32 -> bf16 convert (5 segments, 1 launch) ---------
__global__ __launch_bounds__(256) void cvt5_kernel(
    const float* __restrict__ s0, unsigned short* __restrict__ d0, int n0,
    const float* __restrict__ s1, unsigned short* __restrict__ d1, int n1,
    const float* __restrict__ s2, unsigned short* __restrict__ d2, int n2,
    const float* __restrict__ s3, unsigned short* __restrict__ d3, int n3,
    const float* __restrict__ s4, unsigned short* __restrict__ d4, int n4) {
  int stride = gridDim.x * 256;
  const float* ss[5] = {s0, s1, s2, s3, s4};
  unsigned short* dd[5] = {d0, d1, d2, d3, d4};
  int nn[5] = {n0, n1, n2, n3, n4};
#pragma unroll
  for (int seg = 0; seg < 5; ++seg) {
    const float* s = ss[seg];
    unsigned short* d = dd[seg];
    int n8 = nn[seg];
    for (int i = blockIdx.x * 256 + threadIdx.x; i < n8; i += stride) {
      float4 a = ((const float4*)s)[2 * i];
      float4 b = ((const float4*)s)[2 * i + 1];
      u16x8 o;
      o[0] = f2bf(a.x); o[1] = f2bf(a.y); o[2] = f2bf(a.z); o[3] = f2bf(a.w);
      o[4] = f2bf(b.x); o[5] = f2bf(b.y); o[6] = f2bf(b.z); o[7] = f2bf(b.w);
      ((u16x8*)d)[i] = o;
    }
  }
}

// ---------------- embedding ----------------
__global__ __launch_bounds__(256) void embed_kernel(
    const int* __restrict__ idx, const float* __restrict__ wte,
    const float* __restrict__ wpe, float* __restrict__ x) {
  int row = blockIdx.x;            // 0..2047  (b*1024 + t)
  int tok = idx[row];
  int t = row & 1023;
  float4 a = ((const float4*)(wte + (size_t)tok * 1024))[threadIdx.x];
  float4 p = ((const float4*)(wpe + (size_t)t * 1024))[threadIdx.x];
  a.x += p.x; a.y += p.y; a.z += p.z; a.w += p.w;
  ((float4*)(x + (size_t)row * 1024))[threadIdx.x] = a;
}

// ---------------- layernorm (block per row, C=1024) ----------------
__global__ __launch_bounds__(256) void ln_kernel(
    const float* __restrict__ x, const float* __restrict__ w,
    unsigned short* __restrict__ out) {
  __shared__ float2 red[4];
  int row = blockIdx.x, tid = threadIdx.x;
  float4 v = ((const float4*)(x + (size_t)row * 1024))[tid];
  float s  = v.x + v.y + v.z + v.w;
  float s2 = v.x * v.x + v.y * v.y + v.z * v.z + v.w * v.w;
#pragma unroll
  for (int m = 32; m >= 1; m >>= 1) {
    s  += __shfl_xor(s, m, 64);
    s2 += __shfl_xor(s2, m, 64);
  }
  if ((tid & 63) == 0) red[tid >> 6] = make_float2(s, s2);
  __syncthreads();
  float S = 0.f, S2 = 0.f;
#pragma unroll
  for (int i = 0; i < 4; ++i) { S += red[i].x; S2 += red[i].y; }
  float mu = S * (1.f / 1024.f);
  float var = S2 * (1.f / 1024.f) - mu * mu;
  float rs = rsqrtf(var + 1e-5f);
  float4 wv = ((const float4*)w)[tid];
  ushort4 o;
  o.x = f2bf((v.x - mu) * rs * wv.x);
  o.y = f2bf((v.y - mu) * rs * wv.y);
  o.z = f2bf((v.z - mu) * rs * wv.z);
  o.w = f2bf((v.w - mu) * rs * wv.w);
  ((ushort4*)(out + (size_t)row * 1024))[tid] = o;
}

// ---------------- OLD NT GEMM (f32-weight fallback only) ----------------
template <int MODE, bool WB16>
__global__ __launch_bounds__(256, 2) void gemm_bt(
    const unsigned short* __restrict__ A, const void* __restrict__ Wp,
    void* __restrict__ outp, const float* __restrict__ resid,
    unsigned short* __restrict__ qo, unsigned short* __restrict__ ko,
    unsigned short* __restrict__ vo, int M, int N, int K) {
  __shared__ unsigned short As[2][128 * 64];
  __shared__ unsigned short Bs[2][128 * 64];

  const int tid = threadIdx.x;
  const int lane = tid & 63;
  const int wv = tid >> 6;
  const int lr = lane & 15, lh = lane >> 4;
  const int nbm = M >> 7;
  const int nb = gridDim.x;
  const int bid = blockIdx.x;
  const int swz = (bid & 7) * (nb >> 3) + (bid >> 3);   // bijective XCD chunking
  const int m0 = (swz % nbm) << 7;
  const int n0 = (swz / nbm) << 7;
  const int wm = (wv >> 1) << 6;
  const int wn = (wv & 1) << 6;
  const int nK = K >> 6;

  float4 breg[8];
  const float* Wf = (const float*)Wp;
  const unsigned short* Wb = (const unsigned short*)Wp;

  auto loadB = [&](int kt) {
#pragma unroll
    for (int j = 0; j < 8; ++j) {
      int u = j * 256 + tid;
      int rn = n0 + (u >> 4);
      if (rn >= N) rn = N - 1;
      breg[j] = *(const float4*)(Wf + (size_t)rn * K + kt * 64 + (u & 15) * 4);
    }
  };
  auto writeB = [&](int buf) {
#pragma unroll
    for (int j = 0; j < 8; ++j) {
      int u = j * 256 + tid;
      int row = u >> 4, q = u & 15;
      ushort4 h4;
      h4.x = f2bf(breg[j].x); h4.y = f2bf(breg[j].y);
      h4.z = f2bf(breg[j].z); h4.w = f2bf(breg[j].w);
      int off = row * 128 + ((q * 8) ^ ((row & 7) << 4));
      *(ushort4*)((char*)(&Bs[buf][0]) + off) = h4;
    }
  };
  auto stageA = [&](int buf, int kt) {
    const unsigned short* base = A + (size_t)m0 * K + kt * 64;
#pragma unroll
    for (int j = 0; j < 4; ++j) {
      int u = j * 256 + tid;
      int row = u >> 3, un = u & 7;
      gload16(base + (size_t)row * K + ((un ^ (row & 7)) << 3),
              (char*)(&As[buf][0]) + u * 16);
    }
  };
  auto stageB16 = [&](int buf, int kt) {
#pragma unroll
    for (int j = 0; j < 4; ++j) {
      int u = j * 256 + tid;
      int row = u >> 3, un = u & 7;
      size_t grow = (size_t)(n0 + row);
      if constexpr (MODE == 4) { if ((int)grow >= N) grow = N - 1; }
      gload16(Wb + grow * K + kt * 64 + ((un ^ (row & 7)) << 3),
              (char*)(&Bs[buf][0]) + u * 16);
    }
  };

  f32x4 acc[4][4];
#pragma unroll
  for (int a = 0; a < 4; ++a)
#pragma unroll
    for (int b = 0; b < 4; ++b) acc[a][b] = f32x4{0.f, 0.f, 0.f, 0.f};

  if constexpr (WB16) {
    stageA(0, 0);
    stageB16(0, 0);
  } else {
    loadB(0);
    stageA(0, 0);
    writeB(0);
  }
  __syncthreads();

  for (int kt = 0; kt < nK; ++kt) {
    int cur = kt & 1;
    if constexpr (WB16) {
      if (kt + 1 < nK) { stageA(cur ^ 1, kt + 1); stageB16(cur ^ 1, kt + 1); }
    } else {
      if (kt + 1 < nK) { loadB(kt + 1); stageA(cur ^ 1, kt + 1); }
    }

    bf16x8 af[4][2], bf[4][2];
#pragma unroll
    for (int mi = 0; mi < 4; ++mi)
#pragma unroll
      for (int ks = 0; ks < 2; ++ks) {
        int row = wm + mi * 16 + lr;
        int off = row * 128 + ((ks * 64 + lh * 16) ^ ((row & 7) << 4));
        af[mi][ks] = *(const bf16x8*)((const char*)(&As[cur][0]) + off);
      }
#pragma unroll
    for (int ni = 0; ni < 4; ++ni)
#pragma unroll
      for (int ks = 0; ks < 2; ++ks) {
        int row = wn + ni * 16 + lr;
        int off = row * 128 + ((ks * 64 + lh * 16) ^ ((row & 7) << 4));
        bf[ni][ks] = *(const bf16x8*)((const char*)(&Bs[cur][0]) + off);
      }
#pragma unroll
    for (int ks = 0; ks < 2; ++ks)
#pragma unroll
      for (int mi = 0; mi < 4; ++mi)
#pragma unroll
        for (int ni = 0; ni < 4; ++ni)
          acc[mi][ni] = __builtin_amdgcn_mfma_f32_16x16x32_bf16(
              af[mi][ks], bf[ni][ks], acc[mi][ni], 0, 0, 0);

    if constexpr (!WB16) {
      if (kt + 1 < nK) writeB(cur ^ 1);
    }
    __syncthreads();
  }

#pragma unroll
  for (int mi = 0; mi < 4; ++mi)
#pragma unroll
    for (int ni = 0; ni < 4; ++ni)
#pragma unroll
      for (int r = 0; r < 4; ++r) {
        int grow = m0 + wm + mi * 16 + lh * 4 + r;
        int gcol = n0 + wn + ni * 16 + lr;
        float val = acc[mi][ni][r];
        if constexpr (MODE == 1) val = fmaxf(val, 0.f);
        if constexpr (MODE == 0 || MODE == 1) {
          ((unsigned short*)outp)[(size_t)grow * N + gcol] = f2bf(val);
        } else if constexpr (MODE == 2) {
          ((float*)outp)[(size_t)grow * N + gcol] =
              resid[(size_t)grow * N + gcol] + val;
        } else if constexpr (MODE == 3) {
          int which = gcol >> 10, hh = (gcol >> 6) & 15, dd = gcol & 63;
          int b = grow >> 10, t = grow & 1023;
          unsigned short hv = f2bf(val);
          size_t bh = (size_t)(b * 16 + hh) << 16;
          if (which == 0)      qo[bh + t * 64 + dd] = hv;
          else if (which == 1) ko[bh + t * 64 + dd] = hv;
          else                 vo[bh + dd * 1024 + t] = hv;
        } else {
          if (gcol < N)
            ((float*)outp)[(size_t)grow * (size_t)N + gcol] = val;
        }
      }
}

// ---------------- 128x128 ring-4 counted-vmcnt NT GEMM (bf16 W) ----------------
template <int MODE>
__global__ __launch_bounds__(256, 2) void gemm128_bt(
    const unsigned short* __restrict__ A, const unsigned short* __restrict__ Wb,
    void* __restrict__ outp, const float* __restrict__ resid,
    unsigned short* __restrict__ qo, unsigned short* __restrict__ ko,
    unsigned short* __restrict__ vo, int M, int N, int K) {
  __shared__ unsigned short As[4][128 * 32];
  __shared__ unsigned short Bs[4][128 * 32];

  const int tid = threadIdx.x;
  const int lane = tid & 63;
  const int wv = tid >> 6;
  const int lr = lane & 15, lh = lane >> 4;
  const int nbm = M >> 7;
  const int nb = gridDim.x;
  const int bid = blockIdx.x;
  const int swz = (bid & 7) * (nb >> 3) + (bid >> 3);   // bijective XCD chunking
  const int m0 = (swz % nbm) << 7;
  const int n0 = (swz / nbm) << 7;
  const int wm = (wv >> 1) << 6;
  const int wn = (wv & 1) << 6;
  const int nK = K >> 5;

  size_t aoff[2], boff[2];
  int ldst[2];
#pragma unroll
  for (int j = 0; j < 2; ++j) {
    int u = j * 256 + tid;              // 0..511 lane-loads, 16 B each
    int p = u >> 3, s = u & 7;          // 64 physical rows x 8 slots
    int ss = s ^ (p & 7);
    int arow = m0 + 2 * p + (ss >> 2);
    int brow = n0 + 2 * p + (ss >> 2);
    if (brow >= N) brow = N - 1;
    aoff[j] = (size_t)arow * K + (ss & 3) * 8;
    boff[j] = (size_t)brow * K + (ss & 3) * 8;
    ldst[j] = u * 16;
  }

  auto stage = [&](int buf, int k) {
#pragma unroll
    for (int j = 0; j < 2; ++j)
      gload16(A + aoff[j] + k * 32, (char*)(&As[buf][0]) + ldst[j]);
#pragma unroll
    for (int j = 0; j < 2; ++j)
      gload16(Wb + boff[j] + k * 32, (char*)(&Bs[buf][0]) + ldst[j]);
  };

  f32x4 acc[4][4];
#pragma unroll
  for (int a = 0; a < 4; ++a)
#pragma unroll
    for (int b = 0; b < 4; ++b) acc[a][b] = f32x4{0.f, 0.f, 0.f, 0.f};

  stage(0, 0);
  if (nK > 1) stage(1, 1);
  if (nK > 2) stage(2, 2);
  if (nK > 2)      asm volatile("s_waitcnt vmcnt(8)" ::: "memory");
  else if (nK > 1) asm volatile("s_waitcnt vmcnt(4)" ::: "memory");
  else             asm volatile("s_waitcnt vmcnt(0)" ::: "memory");
  __builtin_amdgcn_s_barrier();
  __builtin_amdgcn_sched_barrier(0);

  for (int kt = 0; kt < nK; ++kt) {
    const int buf = kt & 3;
    bf16x8 af[4], bfr[4];
#pragma unroll
    for (int ni = 0; ni < 4; ++ni) {
      int r = wn + ni * 16 + lr;
      int p = r >> 1;
      int off = p * 128 + (((((r & 1) << 2) | lh) ^ (p & 7)) << 4);
      bfr[ni] = *(const bf16x8*)((const char*)(&Bs[buf][0]) + off);
    }
#pragma unroll
    for (int mi = 0; mi < 4; ++mi) {
      int r = wm + mi * 16 + lr;
      int p = r >> 1;
      int off = p * 128 + (((((r & 1) << 2) | lh) ^ (p & 7)) << 4);
      af[mi] = *(const bf16x8*)((const char*)(&As[buf][0]) + off);
    }
    if (kt + 3 < nK) stage((kt + 3) & 3, kt + 3);

    __builtin_amdgcn_s_setprio(1);
#pragma unroll
    for (int mi = 0; mi < 4; ++mi)
#pragma unroll
      for (int ni = 0; ni < 4; ++ni)
        acc[mi][ni] = __builtin_amdgcn_mfma_f32_16x16x32_bf16(
            af[mi], bfr[ni], acc[mi][ni], 0, 0, 0);
    __builtin_amdgcn_s_setprio(0);

    if (kt + 1 < nK) {
      if (kt + 4 <= nK)      asm volatile("s_waitcnt vmcnt(8)" ::: "memory");
      else if (kt + 3 <= nK) asm volatile("s_waitcnt vmcnt(4)" ::: "memory");
      else                   asm volatile("s_waitcnt vmcnt(0)" ::: "memory");
      __builtin_amdgcn_s_barrier();
      __builtin_amdgcn_sched_barrier(0);
    }
  }

  // epilogue
#pragma unroll
  for (int mi = 0; mi < 4; ++mi)
#pragma unroll
    for (int ni = 0; ni < 4; ++ni)
#pragma unroll
      for (int r = 0; r < 4; ++r) {
        int grow = m0 + wm + mi * 16 + lh * 4 + r;
        int gcol = n0 + wn + ni * 16 + lr;
        float val = acc[mi][ni][r];
        if constexpr (MODE == 1) val = fmaxf(val, 0.f);
        if constexpr (MODE == 0 || MODE == 1) {
          ((unsigned short*)outp)[(size_t)grow * N + gcol] = f2bf(val);
        } else if constexpr (MODE == 2) {
          ((float*)outp)[(size_t)grow * N + gcol] =
              resid[(size_t)grow * N + gcol] + val;
        } else if constexpr (MODE == 3) {
          int which = gcol >> 10, hh = (gcol >> 6) & 15, dd = gcol & 63;
          int b = grow >> 10, t = grow & 1023;
          unsigned short hv = f2bf(val);
          size_t bh = (size_t)(b * 16 + hh) << 16;
          if (which == 0)      qo[bh + t * 64 + dd] = hv;
          else if (which == 1) ko[bh + t * 64 + dd] = hv;
          else                 vo[bh + dd * 1024 + t] = hv;
        } else {
          if (gcol < N)
            ((float*)outp)[(size_t)grow * (size_t)N + gcol] = val;
        }
      }
}

// ---------------- 128x64 ring-4 counted-vmcnt NT GEMM (narrow N) ----------------
template <int MODE>
__global__ __launch_bounds__(256, 2) void gemm64n_bt(
    const unsigned short* __restrict__ A, const unsigned short* __restrict__ Wb,
    void* __restrict__ outp, const float* __restrict__ resid,
    unsigned short* __restrict__ qo, unsigned short* __restrict__ ko,
    unsigned short* __restrict__ vo, int M, int N, int K) {
  __shared__ unsigned short As[4][128 * 32];
  __shared__ unsigned short Bs[4][64 * 32];

  const int tid = threadIdx.x;
  const int lane = tid & 63;
  const int wv = tid >> 6;
  const int lr = lane & 15, lh = lane >> 4;
  const int nbm = M >> 7;
  const int nb = gridDim.x;
  const int bid = blockIdx.x;
  const int swz = (bid & 7) * (nb >> 3) + (bid >> 3);   // bijective XCD chunking
  const int m0 = (swz % nbm) << 7;
  const int n0 = (swz / nbm) << 6;
  const int wm = (wv >> 1) << 6;
  const int wn = (wv & 1) << 5;
  const int nK = K >> 5;

  size_t aoff[2], boff;
  int ldsta[2], ldstb;
#pragma unroll
  for (int j = 0; j < 2; ++j) {
    int u = j * 256 + tid;              // A: 512 lane-loads (64 phys rows)
    int p = u >> 3, s = u & 7;
    int ss = s ^ (p & 7);
    int arow = m0 + 2 * p + (ss >> 2);
    aoff[j] = (size_t)arow * K + (ss & 3) * 8;
    ldsta[j] = u * 16;
  }
  {
    int u = tid;                        // B: 256 lane-loads (32 phys rows)
    int p = u >> 3, s = u & 7;
    int ss = s ^ (p & 7);
    int brow = n0 + 2 * p + (ss >> 2);
    if (brow >= N) brow = N - 1;
    boff = (size_t)brow * K + (ss & 3) * 8;
    ldstb = u * 16;
  }

  auto stage = [&](int buf, int k) {
#pragma unroll
    for (int j = 0; j < 2; ++j)
      gload16(A + aoff[j] + k * 32, (char*)(&As[buf][0]) + ldsta[j]);
    gload16(Wb + boff + k * 32, (char*)(&Bs[buf][0]) + ldstb);
  };

  f32x4 acc[4][2];
#pragma unroll
  for (int a = 0; a < 4; ++a)
#pragma unroll
    for (int b = 0; b < 2; ++b) acc[a][b] = f32x4{0.f, 0.f, 0.f, 0.f};

  stage(0, 0);
  if (nK > 1) stage(1, 1);
  if (nK > 2) stage(2, 2);
  if (nK > 2)      asm volatile("s_waitcnt vmcnt(6)" ::: "memory");
  else if (nK > 1) asm volatile("s_waitcnt vmcnt(3)" ::: "memory");
  else             asm volatile("s_waitcnt vmcnt(0)" ::: "memory");
  __builtin_amdgcn_s_barrier();
  __builtin_amdgcn_sched_barrier(0);

  for (int kt = 0; kt < nK; ++kt) {
    const int buf = kt & 3;
    bf16x8 af[4], bfr[2];
#pragma unroll
    for (int ni = 0; ni < 2; ++ni) {
      int r = wn + ni * 16 + lr;
      int p = r >> 1;
      int off = p * 128 + (((((r & 1) << 2) | lh) ^ (p & 7)) << 4);
      bfr[ni] = *(const bf16x8*)((const char*)(&Bs[buf][0]) + off);
    }
#pragma unroll
    for (int mi = 0; mi < 4; ++mi) {
      int r = wm + mi * 16 + lr;
      int p = r >> 1;
      int off = p * 128 + (((((r & 1) << 2) | lh) ^ (p & 7)) << 4);
      af[mi] = *(const bf16x8*)((const char*)(&As[buf][0]) + off);
    }
    if (kt + 3 < nK) stage((kt + 3) & 3, kt + 3);

    __builtin_amdgcn_s_setprio(1);
#pragma unroll
    for (int mi = 0; mi < 4; ++mi)
#pragma unroll
      for (int ni = 0; ni < 2; ++ni)
        acc[mi][ni] = __builtin_amdgcn_mfma_f32_16x16x32_bf16(
            af[mi], bfr[ni], acc[mi][ni], 0, 0, 0);
    __builtin_amdgcn_s_setprio(0);

    if (kt + 1 < nK) {
      if (kt + 4 <= nK)      asm volatile("s_waitcnt vmcnt(6)" ::: "memory");
      else if (kt + 3 <= nK) asm volatile("s_waitcnt vmcnt(3)" ::: "memory");
      else                   asm volatile("s_waitcnt vmcnt(0)" ::: "memory");
      __builtin_amdgcn_s_barrier();
      __builtin_amdgcn_sched_barrier(0);
    }
  }

  // epilogue
#pragma unroll
  for (int mi = 0; mi < 4; ++mi)
#pragma unroll
    for (int ni = 0; ni < 2; ++ni)
#pragma unroll
      for (int r = 0; r < 4; ++r) {
        int grow = m0 + wm + mi * 16 + lh * 4 + r;
        int gcol = n0 + wn + ni * 16 + lr;
        float val = acc[mi][ni][r];
        if constexpr (MODE == 1) val = fmaxf(val, 0.f);
        if constexpr (MODE == 0 || MODE == 1) {
          ((unsigned short*)outp)[(size_t)grow * N + gcol] = f2bf(val);
        } else if constexpr (MODE == 2) {
          ((float*)outp)[(size_t)grow * N + gcol] =
              resid[(size_t)grow * N + gcol] + val;
        } else if constexpr (MODE == 3) {
          int which = gcol >> 10, hh = (gcol >> 6) & 15, dd = gcol & 63;
          int b = grow >> 10, t = grow & 1023;
          unsigned short hv = f2bf(val);
          size_t bh = (size_t)(b * 16 + hh) << 16;
          if (which == 0)      qo[bh + t * 64 + dd] = hv;
          else if (which == 1) ko[bh + t * 64 + dd] = hv;
          else                 vo[bh + dd * 1024 + t] = hv;
        } else {
          if (gcol < N)
            ((float*)outp)[(size_t)grow * (size_t)N + gcol] = val;
        }
      }
}

// ---------------- 256x256 ring-2 NT GEMM (head) ------------------------------
// Same 256^2 tile geometry as the ring-4 version (nbm=8 -> minimal weight
// re-fetch; FETCH ~176 MB, L3-absorbed), but LDS halved to ring-2 (64 KiB)
// -> 2 blocks/CU. The per-tile vmcnt(0) drain (m97 structure) is hidden by
// the co-resident block's MFMAs (m114 implicit overlap) — the hiding that
// was impossible at 1 block/CU. Hazards: buf (k+1)&1 staged in iter k was
// last ds_read in iter k-1 (reads done before end-of-(k-1) barrier); ds_read
// of buf k&1 covered by previous iteration's vmcnt(0)+barrier.
__global__ __launch_bounds__(512, 2) void gemm256_bt(
    const unsigned short* __restrict__ A, const unsigned short* __restrict__ Wb,
    float* __restrict__ out, int M, int N, int K) {
  __shared__ unsigned short As[2][256 * 32];
  __shared__ unsigned short Bs[2][256 * 32];

  const int tid = threadIdx.x;
  const int lane = tid & 63;
  const int wv = tid >> 6;
  const int lr = lane & 15, lh = lane >> 4;
  const int wm = (wv >> 2) * 128;   // warp_m in {0,1}
  const int wn = (wv & 3) * 64;     // warp_n in {0..3}
  const int nbm = M >> 8;
  const int nb = gridDim.x;
  const int bid = blockIdx.x;
  const int swz = (bid & 7) * (nb >> 3) + (bid >> 3);  // bijective XCD chunking
  const int m0 = (swz % nbm) << 8;
  const int n0 = (swz / nbm) << 8;
  const int nK = K >> 5;

  size_t aoff[2], boff[2];
  int ldst[2];
#pragma unroll
  for (int j = 0; j < 2; ++j) {
    int u = j * 512 + tid;
    int p = u >> 3, s = u & 7;
    int ss = s ^ (p & 7);            // inverse swizzle on the source side
    int arow = m0 + 2 * p + (ss >> 2);
    int brow = n0 + 2 * p + (ss >> 2);
    if (brow >= N) brow = N - 1;
    aoff[j] = (size_t)arow * K + (ss & 3) * 8;
    boff[j] = (size_t)brow * K + (ss & 3) * 8;
    ldst[j] = u * 16;
  }

  auto stage = [&](int buf, int k) {
#pragma unroll
    for (int j = 0; j < 2; ++j)
      gload16(A + aoff[j] + k * 32, (char*)(&As[buf][0]) + ldst[j]);
#pragma unroll
    for (int j = 0; j < 2; ++j)
      gload16(Wb + boff[j] + k * 32, (char*)(&Bs[buf][0]) + ldst[j]);
  };

  f32x4 acc[8][4];
#pragma unroll
  for (int a = 0; a < 8; ++a)
#pragma unroll
    for (int b = 0; b < 4; ++b) acc[a][b] = f32x4{0.f, 0.f, 0.f, 0.f};

  stage(0, 0);
  asm volatile("s_waitcnt vmcnt(0)" ::: "memory");
  __builtin_amdgcn_s_barrier();
  __builtin_amdgcn_sched_barrier(0);

  for (int k = 0; k < nK; ++k) {
    const int buf = k & 1;
    if (k + 1 < nK) stage(buf ^ 1, k + 1);

    bf16x8 af[8], bfr[4];
#pragma unroll
    for (int ni = 0; ni < 4; ++ni) {
      int r = wn + ni * 16 + lr;
      int p = r >> 1;
      int off = p * 128 + (((((r & 1) << 2) | lh) ^ (p & 7)) << 4);
      bfr[ni] = *(const bf16x8*)((const char*)(&Bs[buf][0]) + off);
    }
#pragma unroll
    for (int mi = 0; mi < 8; ++mi) {
      int r = wm + mi * 16 + lr;
      int p = r >> 1;
      int off = p * 128 + (((((r & 1) << 2) | lh) ^ (p & 7)) << 4);
      af[mi] = *(const bf16x8*)((const char*)(&As[buf][0]) + off);
    }

    __builtin_amdgcn_s_setprio(1);
#pragma unroll
    for (int mi = 0; mi < 8; ++mi)
#pragma unroll
      for (int ni = 0; ni < 4; ++ni)
        acc[mi][ni] = __builtin_amdgcn_mfma_f32_16x16x32_bf16(
            af[mi], bfr[ni], acc[mi][ni], 0, 0, 0);
    __builtin_amdgcn_s_setprio(0);

    if (k + 1 < nK) {
      asm volatile("s_waitcnt vmcnt(0)" ::: "memory");
      __builtin_amdgcn_s_barrier();
      __builtin_amdgcn_sched_barrier(0);
    }
  }

#pragma unroll
  for (int mi = 0; mi < 8; ++mi)
#pragma unroll
    for (int ni = 0; ni < 4; ++ni)
#pragma unroll
      for (int r = 0; r < 4; ++r) {
        int grow = m0 + wm + mi * 16 + lh * 4 + r;
        int gcol = n0 + wn + ni * 16 + lr;
        if (gcol < N) out[(size_t)grow * (size_t)N + gcol] = acc[mi][ni][r];
      }
}

// ---------------- flash attention, causal-balanced, 2 waves/block -------------
__global__ __launch_bounds__(128, 2) void attn_kernel(
    const unsigned short* __restrict__ qb, const unsigned short* __restrict__ kb,
    const unsigned short* __restrict__ vt, unsigned short* __restrict__ yb) {
  __shared__ unsigned short Ks[2][64 * 64];
  __shared__ unsigned short Vs[2][64 * 64];
  __shared__ unsigned short Ps[2][32 * 64];

  const int tid = threadIdx.x, lane = tid & 63, wv = tid >> 6;
  const int lr = lane & 15, lh = lane >> 4;
  const int bid = blockIdx.x;
  const int bh = bid & 31;
  const int rest = bid >> 5;
  const int j = rest >> 1, hf = rest & 1;
  const int sub = (hf * 2 + wv) * 16;
  const int rb0 = j * 64 + sub;              // chunk A rows (mi=0)
  const int rb1 = (15 - j) * 64 + sub;       // chunk B rows (mi=1)
  const unsigned short* qp = qb + ((size_t)bh << 16);
  const unsigned short* kp = kb + ((size_t)bh << 16);
  const unsigned short* vp = vt + ((size_t)bh << 16);

  bf16x8 qf[2][2];
#pragma unroll
  for (int mi = 0; mi < 2; ++mi)
#pragma unroll
    for (int ks = 0; ks < 2; ++ks) {
      int row = (mi ? rb1 : rb0) + lr;
      qf[mi][ks] = *(const bf16x8*)(qp + (size_t)row * 64 + ks * 32 + lh * 8);
    }

  f32x4 o[2][4];
  float mr[2][4], lsum[2][4];
#pragma unroll
  for (int mi = 0; mi < 2; ++mi) {
#pragma unroll
    for (int di = 0; di < 4; ++di) o[mi][di] = f32x4{0.f, 0.f, 0.f, 0.f};
#pragma unroll
    for (int r = 0; r < 4; ++r) { mr[mi][r] = -1e30f; lsum[mi][r] = 0.f; }
  }

  const int ntiles = 16 - j;

  auto stageKV = [&](int buf, int t) {
    int kv0 = t << 6;
#pragma unroll
    for (int jj = 0; jj < 4; ++jj) {
      int u = jj * 128 + tid;
      int row = u >> 3, un = u & 7;
      gload16(kp + (size_t)(kv0 + row) * 64 + ((un ^ (row & 7)) << 3),
              (char*)(&Ks[buf][0]) + u * 16);
      gload16(vp + (size_t)row * 1024 + kv0 + ((un ^ (row & 7)) << 3),
              (char*)(&Vs[buf][0]) + u * 16);
    }
  };

  stageKV(0, 0);

  for (int t = 0; t < ntiles; ++t) {
    __syncthreads();
    if (t + 1 < ntiles) stageKV((t + 1) & 1, t + 1);
    int cur = t & 1;
    int kv0 = t << 6;
    const bool act0 = (t <= j);   // chunk A active this tile (block-uniform)

    f32x4 s[2][4];
#pragma unroll
    for (int mi = 0; mi < 2; ++mi)
#pragma unroll
      for (int ni = 0; ni < 4; ++ni) s[mi][ni] = f32x4{0.f, 0.f, 0.f, 0.f};

    bf16x8 kf[4][2];
#pragma unroll
    for (int ni = 0; ni < 4; ++ni)
#pragma unroll
      for (int ks = 0; ks < 2; ++ks) {
        int row = ni * 16 + lr;
        int off = row * 128 + ((ks * 64 + lh * 16) ^ ((row & 7) << 4));
        kf[ni][ks] = *(const bf16x8*)((const char*)(&Ks[cur][0]) + off);
      }
#pragma unroll
    for (int ks = 0; ks < 2; ++ks)
#pragma unroll
      for (int ni = 0; ni < 4; ++ni) {
        if (act0)
          s[0][ni] = __builtin_amdgcn_mfma_f32_16x16x32_bf16(
              qf[0][ks], kf[ni][ks], s[0][ni], 0, 0, 0);
        s[1][ni] = __builtin_amdgcn_mfma_f32_16x16x32_bf16(
            qf[1][ks], kf[ni][ks], s[1][ni], 0, 0, 0);
      }

    // scale + causal mask + online softmax (per mi; mi=0 gated)
#pragma unroll
    for (int mi = 0; mi < 2; ++mi) {
      if (mi == 0 && !act0) continue;
      const int rb = mi ? rb1 : rb0;
#pragma unroll
      for (int r = 0; r < 4; ++r) {
        int rowq = rb + lh * 4 + r;
        float xv[4];
        float pm = -1e30f;
#pragma unroll
        for (int ni = 0; ni < 4; ++ni) {
          int col = kv0 + ni * 16 + lr;
          float xx = s[mi][ni][r] * 0.125f;
          if (col > rowq) xx = -1e30f;
          xv[ni] = xx;
          pm = fmaxf(pm, xx);
        }
#pragma unroll
        for (int msk = 1; msk < 16; msk <<= 1)
          pm = fmaxf(pm, __shfl_xor(pm, msk, 64));
        float mnew = fmaxf(mr[mi][r], pm);
        float al = exp2f((mr[mi][r] - mnew) * LOG2E);
        mr[mi][r] = mnew;
        float ps = 0.f;
#pragma unroll
        for (int ni = 0; ni < 4; ++ni) {
          float p = exp2f((xv[ni] - mnew) * LOG2E);
          s[mi][ni][r] = p;
          ps += p;
        }
#pragma unroll
        for (int msk = 1; msk < 16; msk <<= 1) ps += __shfl_xor(ps, msk, 64);
        lsum[mi][r] = lsum[mi][r] * al + ps;
#pragma unroll
        for (int di = 0; di < 4; ++di) o[mi][di][r] *= al;
      }
    }

    // P (C-layout) -> per-wave LDS (A-frag layout), swizzled; mi=0 gated
#pragma unroll
    for (int mi = 0; mi < 2; ++mi) {
      if (mi == 0 && !act0) continue;
#pragma unroll
      for (int ni = 0; ni < 4; ++ni)
#pragma unroll
        for (int r = 0; r < 4; ++r) {
          int row = mi * 16 + lh * 4 + r;
          int off = row * 128 + (((ni * 16 + lr) * 2) ^ ((row & 7) << 4));
          *(unsigned short*)((char*)(&Ps[wv][0]) + off) = f2bf(s[mi][ni][r]);
        }
    }

    bf16x8 pf[2][2], vf[4][2];
#pragma unroll
    for (int mi = 0; mi < 2; ++mi) {
      if (mi == 0 && !act0) continue;
#pragma unroll
      for (int ks = 0; ks < 2; ++ks) {
        int row = mi * 16 + lr;
        int off = row * 128 + ((ks * 64 + lh * 16) ^ ((row & 7) << 4));
        pf[mi][ks] = *(const bf16x8*)((const char*)(&Ps[wv][0]) + off);
      }
    }
#pragma unroll
    for (int di = 0; di < 4; ++di)
#pragma unroll
      for (int ks = 0; ks < 2; ++ks) {
        int row = di * 16 + lr;
        int off = row * 128 + ((ks * 64 + lh * 16) ^ ((row & 7) << 4));
        vf[di][ks] = *(const bf16x8*)((const char*)(&Vs[cur][0]) + off);
      }
#pragma unroll
    for (int ks = 0; ks < 2; ++ks)
#pragma unroll
      for (int di = 0; di < 4; ++di) {
        if (act0)
          o[0][di] = __builtin_amdgcn_mfma_f32_16x16x32_bf16(
              pf[0][ks], vf[di][ks], o[0][di], 0, 0, 0);
        o[1][di] = __builtin_amdgcn_mfma_f32_16x16x32_bf16(
            pf[1][ks], vf[di][ks], o[1][di], 0, 0, 0);
      }
  }

  int b = bh >> 4, hh = bh & 15;
#pragma unroll
  for (int mi = 0; mi < 2; ++mi)
#pragma unroll
    for (int r = 0; r < 4; ++r) {
      float inv = 1.f / lsum[mi][r];
      int rowq = (mi ? rb1 : rb0) + lh * 4 + r;
      size_t mg = (size_t)(b * 1024 + rowq) * 1024 + hh * 64;
#pragma unroll
      for (int di = 0; di < 4; ++di)
        yb[mg + di * 16 + lr] = f2bf(o[mi][di][r] * inv);
    }
}

// ---------------- launch ----------------
extern "C" void kernel_launch(void* const* d_in, const int* in_sizes, int n_in,
                              void* d_out, int out_size, void* d_ws,
                              size_t ws_size, hipStream_t stream) {
  const int*   idx  = (const int*)d_in[0];
  const float* wte  = (const float*)d_in[1];
  const float* wpe  = (const float*)d_in[2];
  const float* ln1w = (const float*)d_in[3];
  const float* attnw= (const float*)d_in[4];
  const float* aprj = (const float*)d_in[5];
  const float* ln2w = (const float*)d_in[6];
  const float* fcw  = (const float*)d_in[7];
  const float* mprj = (const float*)d_in[8];
  const float* lnfw = (const float*)d_in[9];
  const float* hw   = (const float*)d_in[10];
  float* out = (float*)d_out;
  char* ws = (char*)d_ws;

  float* x            = (float*)ws;                                  // 8 MB
  unsigned short* h   = (unsigned short*)(ws + ((size_t)8 << 20));   // 4 MB
  unsigned short* qbf = (unsigned short*)(ws + ((size_t)12 << 20));  // 4 MB
  unsigned short* kbf = (unsigned short*)(ws + ((size_t)16 << 20));  // 4 MB
  unsigned short* vtb = (unsigned short*)(ws + ((size_t)20 << 20));  // 4 MB
  unsigned short* ybf = (unsigned short*)(ws + ((size_t)24 << 20));  // 4 MB
  unsigned short* mhb = (unsigned short*)(ws + ((size_t)12 << 20));  // 16 MB, aliases qkv/y (safe by schedule)

  // bf16 weight copies
  size_t off = (size_t)28 << 20;
  unsigned short* attnw16 = (unsigned short*)(ws + off); off += (size_t)4 * 3072 * 1024 * 2;
  unsigned short* aprj16  = (unsigned short*)(ws + off); off += (size_t)4 * 1024 * 1024 * 2;
  unsigned short* fcw16   = (unsigned short*)(ws + off); off += (size_t)4 * 4096 * 1024 * 2;
  unsigned short* mprj16  = (unsigned short*)(ws + off); off += (size_t)4 * 1024 * 4096 * 2;
  unsigned short* hw16    = (unsigned short*)(ws + off); off += (size_t)50257 * 1024 * 2;
  const bool b16 = ws_size >= off;

  embed_kernel<<<2048, 256, 0, stream>>>(idx, wte, wpe, x);

  if (b16) {
    cvt5_kernel<<<2048, 256, 0, stream>>>(
        attnw, attnw16, 4 * 3072 * 1024 / 8,
        aprj,  aprj16,  4 * 1024 * 1024 / 8,
        fcw,   fcw16,   4 * 4096 * 1024 / 8,
        mprj,  mprj16,  4 * 1024 * 4096 / 8,
        hw,    hw16,    50257 * 1024 / 8);
  }

  for (int l = 0; l < 4; ++l) {
    ln_kernel<<<2048, 256, 0, stream>>>(x, ln1w + l * 1024, h);
    if (b16)
      gemm64n_bt<3><<<16 * 48, 256, 0, stream>>>(
          h, attnw16 + (size_t)l * 3072 * 1024, nullptr, nullptr, qbf, kbf,
          vtb, 2048, 3072, 1024);
    else
      gemm_bt<3, false><<<16 * 24, 256, 0, stream>>>(
          h, attnw + (size_t)l * 3072 * 1024, nullptr, nullptr, qbf, kbf, vtb,
          2048, 3072, 1024);
    attn_kernel<<<512, 128, 0, stream>>>(qbf, kbf, vtb, ybf);
    if (b16)
      gemm64n_bt<2><<<16 * 16, 256, 0, stream>>>(
          ybf, aprj16 + (size_t)l * 1024 * 1024, x, x, nullptr, nullptr,
          nullptr, 2048, 1024, 1024);
    else
      gemm_bt<2, false><<<16 * 8, 256, 0, stream>>>(
          ybf, aprj + (size_t)l * 1024 * 1024, x, x, nullptr, nullptr, nullptr,
          2048, 1024, 1024);
    ln_kernel<<<2048, 256, 0, stream>>>(x, ln2w + l * 1024, h);
    if (b16)
      gemm128_bt<1><<<16 * 32, 256, 0, stream>>>(
          h, fcw16 + (size_t)l * 4096 * 1024, mhb, nullptr, nullptr, nullptr,
          nullptr, 2048, 4096, 1024);
    else
      gemm_bt<1, false><<<16 * 32, 256, 0, stream>>>(
          h, fcw + (size_t)l * 4096 * 1024, mhb, nullptr, nullptr, nullptr,
          nullptr, 2048, 4096, 1024);
    if (b16)
      gemm64n_bt<2><<<16 * 16, 256, 0, stream>>>(
          mhb, mprj16 + (size_t)l * 1024 * 4096, x, x, nullptr, nullptr,
          nullptr, 2048, 1024, 4096);
    else
      gemm_bt<2, false><<<16 * 8, 256, 0, stream>>>(
          mhb, mprj + (size_t)l * 1024 * 4096, x, x, nullptr, nullptr, nullptr,
          2048, 1024, 4096);
  }

  ln_kernel<<<2048, 256, 0, stream>>>(x, lnfw, h);
  if (b16)
    gemm256_bt<<<8 * 197, 512, 0, stream>>>(h, hw16, out, 2048, 50257, 1024);
  else
    gemm_bt<4, false><<<16 * 393, 256, 0, stream>>>(
        h, hw, out, nullptr, nullptr, nullptr, nullptr, 2048, 50257, 1024);
}

// Round 9
// 1204.313 us; speedup vs baseline: 1.0566x; 1.0566x over previous
//
#include <hip/hip_runtime.h>

typedef __bf16 bf16x8 __attribute__((ext_vector_type(8)));
typedef float f32x4 __attribute__((ext_vector_type(4)));
typedef unsigned short u16x8 __attribute__((ext_vector_type(8)));

#define LOG2E 1.4426950408889634f

__device__ __forceinline__ unsigned short f2bf(float f) {
  union { float f; unsigned u; } v; v.f = f;
  return (unsigned short)((v.u + 0x7fffu + ((v.u >> 16) & 1u)) >> 16);
}

__device__ __forceinline__ void gload16(const void* g, void* l) {
  __builtin_amdgcn_global_load_lds(
      (const __attribute__((address_space(1))) unsigned int*)g,
      (__attribute__((address_space(3))) unsigned int*)l, 16, 0, 0);
}

// ---------------- weight f32 -> bf16 convert (5 segments, 1 launch) ---------
__global__ __launch_bounds__(256) void cvt5_kernel(
    const float* __restrict__ s0, unsigned short* __restrict__ d0, int n0,
    const float* __restrict__ s1, unsigned short* __restrict__ d1, int n1,
    const float* __restrict__ s2, unsigned short* __restrict__ d2, int n2,
    const float* __restrict__ s3, unsigned short* __restrict__ d3, int n3,
    const float* __restrict__ s4, unsigned short* __restrict__ d4, int n4) {
  int stride = gridDim.x * 256;
  const float* ss[5] = {s0, s1, s2, s3, s4};
  unsigned short* dd[5] = {d0, d1, d2, d3, d4};
  int nn[5] = {n0, n1, n2, n3, n4};
#pragma unroll
  for (int seg = 0; seg < 5; ++seg) {
    const float* s = ss[seg];
    unsigned short* d = dd[seg];
    int n8 = nn[seg];
    for (int i = blockIdx.x * 256 + threadIdx.x; i < n8; i += stride) {
      float4 a = ((const float4*)s)[2 * i];
      float4 b = ((const float4*)s)[2 * i + 1];
      u16x8 o;
      o[0] = f2bf(a.x); o[1] = f2bf(a.y); o[2] = f2bf(a.z); o[3] = f2bf(a.w);
      o[4] = f2bf(b.x); o[5] = f2bf(b.y); o[6] = f2bf(b.z); o[7] = f2bf(b.w);
      ((u16x8*)d)[i] = o;
    }
  }
}

// ---------------- embedding ----------------
__global__ __launch_bounds__(256) void embed_kernel(
    const int* __restrict__ idx, const float* __restrict__ wte,
    const float* __restrict__ wpe, float* __restrict__ x) {
  int row = blockIdx.x;            // 0..2047  (b*1024 + t)
  int tok = idx[row];
  int t = row & 1023;
  float4 a = ((const float4*)(wte + (size_t)tok * 1024))[threadIdx.x];
  float4 p = ((const float4*)(wpe + (size_t)t * 1024))[threadIdx.x];
  a.x += p.x; a.y += p.y; a.z += p.z; a.w += p.w;
  ((float4*)(x + (size_t)row * 1024))[threadIdx.x] = a;
}

// ---------------- layernorm (block per row, C=1024) ----------------
__global__ __launch_bounds__(256) void ln_kernel(
    const float* __restrict__ x, const float* __restrict__ w,
    unsigned short* __restrict__ out) {
  __shared__ float2 red[4];
  int row = blockIdx.x, tid = threadIdx.x;
  float4 v = ((const float4*)(x + (size_t)row * 1024))[tid];
  float s  = v.x + v.y + v.z + v.w;
  float s2 = v.x * v.x + v.y * v.y + v.z * v.z + v.w * v.w;
#pragma unroll
  for (int m = 32; m >= 1; m >>= 1) {
    s  += __shfl_xor(s, m, 64);
    s2 += __shfl_xor(s2, m, 64);
  }
  if ((tid & 63) == 0) red[tid >> 6] = make_float2(s, s2);
  __syncthreads();
  float S = 0.f, S2 = 0.f;
#pragma unroll
  for (int i = 0; i < 4; ++i) { S += red[i].x; S2 += red[i].y; }
  float mu = S * (1.f / 1024.f);
  float var = S2 * (1.f / 1024.f) - mu * mu;
  float rs = rsqrtf(var + 1e-5f);
  float4 wv = ((const float4*)w)[tid];
  ushort4 o;
  o.x = f2bf((v.x - mu) * rs * wv.x);
  o.y = f2bf((v.y - mu) * rs * wv.y);
  o.z = f2bf((v.z - mu) * rs * wv.z);
  o.w = f2bf((v.w - mu) * rs * wv.w);
  ((ushort4*)(out + (size_t)row * 1024))[tid] = o;
}

// ---------------- OLD NT GEMM (f32-weight fallback only) ----------------
template <int MODE, bool WB16>
__global__ __launch_bounds__(256, 2) void gemm_bt(
    const unsigned short* __restrict__ A, const void* __restrict__ Wp,
    void* __restrict__ outp, const float* __restrict__ resid,
    unsigned short* __restrict__ qo, unsigned short* __restrict__ ko,
    unsigned short* __restrict__ vo, int M, int N, int K) {
  __shared__ unsigned short As[2][128 * 64];
  __shared__ unsigned short Bs[2][128 * 64];

  const int tid = threadIdx.x;
  const int lane = tid & 63;
  const int wv = tid >> 6;
  const int lr = lane & 15, lh = lane >> 4;
  const int nbm = M >> 7;
  const int nb = gridDim.x;
  const int bid = blockIdx.x;
  const int swz = (bid & 7) * (nb >> 3) + (bid >> 3);   // bijective XCD chunking
  const int m0 = (swz % nbm) << 7;
  const int n0 = (swz / nbm) << 7;
  const int wm = (wv >> 1) << 6;
  const int wn = (wv & 1) << 6;
  const int nK = K >> 6;

  float4 breg[8];
  const float* Wf = (const float*)Wp;
  const unsigned short* Wb = (const unsigned short*)Wp;

  auto loadB = [&](int kt) {
#pragma unroll
    for (int j = 0; j < 8; ++j) {
      int u = j * 256 + tid;
      int rn = n0 + (u >> 4);
      if (rn >= N) rn = N - 1;
      breg[j] = *(const float4*)(Wf + (size_t)rn * K + kt * 64 + (u & 15) * 4);
    }
  };
  auto writeB = [&](int buf) {
#pragma unroll
    for (int j = 0; j < 8; ++j) {
      int u = j * 256 + tid;
      int row = u >> 4, q = u & 15;
      ushort4 h4;
      h4.x = f2bf(breg[j].x); h4.y = f2bf(breg[j].y);
      h4.z = f2bf(breg[j].z); h4.w = f2bf(breg[j].w);
      int off = row * 128 + ((q * 8) ^ ((row & 7) << 4));
      *(ushort4*)((char*)(&Bs[buf][0]) + off) = h4;
    }
  };
  auto stageA = [&](int buf, int kt) {
    const unsigned short* base = A + (size_t)m0 * K + kt * 64;
#pragma unroll
    for (int j = 0; j < 4; ++j) {
      int u = j * 256 + tid;
      int row = u >> 3, un = u & 7;
      gload16(base + (size_t)row * K + ((un ^ (row & 7)) << 3),
              (char*)(&As[buf][0]) + u * 16);
    }
  };
  auto stageB16 = [&](int buf, int kt) {
#pragma unroll
    for (int j = 0; j < 4; ++j) {
      int u = j * 256 + tid;
      int row = u >> 3, un = u & 7;
      size_t grow = (size_t)(n0 + row);
      if constexpr (MODE == 4) { if ((int)grow >= N) grow = N - 1; }
      gload16(Wb + grow * K + kt * 64 + ((un ^ (row & 7)) << 3),
              (char*)(&Bs[buf][0]) + u * 16);
    }
  };

  f32x4 acc[4][4];
#pragma unroll
  for (int a = 0; a < 4; ++a)
#pragma unroll
    for (int b = 0; b < 4; ++b) acc[a][b] = f32x4{0.f, 0.f, 0.f, 0.f};

  if constexpr (WB16) {
    stageA(0, 0);
    stageB16(0, 0);
  } else {
    loadB(0);
    stageA(0, 0);
    writeB(0);
  }
  __syncthreads();

  for (int kt = 0; kt < nK; ++kt) {
    int cur = kt & 1;
    if constexpr (WB16) {
      if (kt + 1 < nK) { stageA(cur ^ 1, kt + 1); stageB16(cur ^ 1, kt + 1); }
    } else {
      if (kt + 1 < nK) { loadB(kt + 1); stageA(cur ^ 1, kt + 1); }
    }

    bf16x8 af[4][2], bf[4][2];
#pragma unroll
    for (int mi = 0; mi < 4; ++mi)
#pragma unroll
      for (int ks = 0; ks < 2; ++ks) {
        int row = wm + mi * 16 + lr;
        int off = row * 128 + ((ks * 64 + lh * 16) ^ ((row & 7) << 4));
        af[mi][ks] = *(const bf16x8*)((const char*)(&As[cur][0]) + off);
      }
#pragma unroll
    for (int ni = 0; ni < 4; ++ni)
#pragma unroll
      for (int ks = 0; ks < 2; ++ks) {
        int row = wn + ni * 16 + lr;
        int off = row * 128 + ((ks * 64 + lh * 16) ^ ((row & 7) << 4));
        bf[ni][ks] = *(const bf16x8*)((const char*)(&Bs[cur][0]) + off);
      }
#pragma unroll
    for (int ks = 0; ks < 2; ++ks)
#pragma unroll
      for (int mi = 0; mi < 4; ++mi)
#pragma unroll
        for (int ni = 0; ni < 4; ++ni)
          acc[mi][ni] = __builtin_amdgcn_mfma_f32_16x16x32_bf16(
              af[mi][ks], bf[ni][ks], acc[mi][ni], 0, 0, 0);

    if constexpr (!WB16) {
      if (kt + 1 < nK) writeB(cur ^ 1);
    }
    __syncthreads();
  }

#pragma unroll
  for (int mi = 0; mi < 4; ++mi)
#pragma unroll
    for (int ni = 0; ni < 4; ++ni)
#pragma unroll
      for (int r = 0; r < 4; ++r) {
        int grow = m0 + wm + mi * 16 + lh * 4 + r;
        int gcol = n0 + wn + ni * 16 + lr;
        float val = acc[mi][ni][r];
        if constexpr (MODE == 1) val = fmaxf(val, 0.f);
        if constexpr (MODE == 0 || MODE == 1) {
          ((unsigned short*)outp)[(size_t)grow * N + gcol] = f2bf(val);
        } else if constexpr (MODE == 2) {
          ((float*)outp)[(size_t)grow * N + gcol] =
              resid[(size_t)grow * N + gcol] + val;
        } else if constexpr (MODE == 3) {
          int which = gcol >> 10, hh = (gcol >> 6) & 15, dd = gcol & 63;
          int b = grow >> 10, t = grow & 1023;
          unsigned short hv = f2bf(val);
          size_t bh = (size_t)(b * 16 + hh) << 16;
          if (which == 0)      qo[bh + t * 64 + dd] = hv;
          else if (which == 1) ko[bh + t * 64 + dd] = hv;
          else                 vo[bh + dd * 1024 + t] = hv;
        } else {
          if (gcol < N)
            ((float*)outp)[(size_t)grow * (size_t)N + gcol] = val;
        }
      }
}

// ---------------- 128x128 ring-4 counted-vmcnt NT GEMM (bf16 W) ----------------
template <int MODE>
__global__ __launch_bounds__(256, 2) void gemm128_bt(
    const unsigned short* __restrict__ A, const unsigned short* __restrict__ Wb,
    void* __restrict__ outp, const float* __restrict__ resid,
    unsigned short* __restrict__ qo, unsigned short* __restrict__ ko,
    unsigned short* __restrict__ vo, int M, int N, int K) {
  __shared__ unsigned short As[4][128 * 32];
  __shared__ unsigned short Bs[4][128 * 32];

  const int tid = threadIdx.x;
  const int lane = tid & 63;
  const int wv = tid >> 6;
  const int lr = lane & 15, lh = lane >> 4;
  const int nbm = M >> 7;
  const int nb = gridDim.x;
  const int bid = blockIdx.x;
  const int swz = (bid & 7) * (nb >> 3) + (bid >> 3);   // bijective XCD chunking
  const int m0 = (swz % nbm) << 7;
  const int n0 = (swz / nbm) << 7;
  const int wm = (wv >> 1) << 6;
  const int wn = (wv & 1) << 6;
  const int nK = K >> 5;

  size_t aoff[2], boff[2];
  int ldst[2];
#pragma unroll
  for (int j = 0; j < 2; ++j) {
    int u = j * 256 + tid;              // 0..511 lane-loads, 16 B each
    int p = u >> 3, s = u & 7;          // 64 physical rows x 8 slots
    int ss = s ^ (p & 7);
    int arow = m0 + 2 * p + (ss >> 2);
    int brow = n0 + 2 * p + (ss >> 2);
    if (brow >= N) brow = N - 1;
    aoff[j] = (size_t)arow * K + (ss & 3) * 8;
    boff[j] = (size_t)brow * K + (ss & 3) * 8;
    ldst[j] = u * 16;
  }

  auto stage = [&](int buf, int k) {
#pragma unroll
    for (int j = 0; j < 2; ++j)
      gload16(A + aoff[j] + k * 32, (char*)(&As[buf][0]) + ldst[j]);
#pragma unroll
    for (int j = 0; j < 2; ++j)
      gload16(Wb + boff[j] + k * 32, (char*)(&Bs[buf][0]) + ldst[j]);
  };

  f32x4 acc[4][4];
#pragma unroll
  for (int a = 0; a < 4; ++a)
#pragma unroll
    for (int b = 0; b < 4; ++b) acc[a][b] = f32x4{0.f, 0.f, 0.f, 0.f};

  stage(0, 0);
  if (nK > 1) stage(1, 1);
  if (nK > 2) stage(2, 2);
  if (nK > 2)      asm volatile("s_waitcnt vmcnt(8)" ::: "memory");
  else if (nK > 1) asm volatile("s_waitcnt vmcnt(4)" ::: "memory");
  else             asm volatile("s_waitcnt vmcnt(0)" ::: "memory");
  __builtin_amdgcn_s_barrier();
  __builtin_amdgcn_sched_barrier(0);

  for (int kt = 0; kt < nK; ++kt) {
    const int buf = kt & 3;
    bf16x8 af[4], bfr[4];
#pragma unroll
    for (int ni = 0; ni < 4; ++ni) {
      int r = wn + ni * 16 + lr;
      int p = r >> 1;
      int off = p * 128 + (((((r & 1) << 2) | lh) ^ (p & 7)) << 4);
      bfr[ni] = *(const bf16x8*)((const char*)(&Bs[buf][0]) + off);
    }
#pragma unroll
    for (int mi = 0; mi < 4; ++mi) {
      int r = wm + mi * 16 + lr;
      int p = r >> 1;
      int off = p * 128 + (((((r & 1) << 2) | lh) ^ (p & 7)) << 4);
      af[mi] = *(const bf16x8*)((const char*)(&As[buf][0]) + off);
    }
    if (kt + 3 < nK) stage((kt + 3) & 3, kt + 3);

    __builtin_amdgcn_s_setprio(1);
#pragma unroll
    for (int mi = 0; mi < 4; ++mi)
#pragma unroll
      for (int ni = 0; ni < 4; ++ni)
        acc[mi][ni] = __builtin_amdgcn_mfma_f32_16x16x32_bf16(
            af[mi], bfr[ni], acc[mi][ni], 0, 0, 0);
    __builtin_amdgcn_s_setprio(0);

    if (kt + 1 < nK) {
      if (kt + 4 <= nK)      asm volatile("s_waitcnt vmcnt(8)" ::: "memory");
      else if (kt + 3 <= nK) asm volatile("s_waitcnt vmcnt(4)" ::: "memory");
      else                   asm volatile("s_waitcnt vmcnt(0)" ::: "memory");
      __builtin_amdgcn_s_barrier();
      __builtin_amdgcn_sched_barrier(0);
    }
  }

  // epilogue
#pragma unroll
  for (int mi = 0; mi < 4; ++mi)
#pragma unroll
    for (int ni = 0; ni < 4; ++ni)
#pragma unroll
      for (int r = 0; r < 4; ++r) {
        int grow = m0 + wm + mi * 16 + lh * 4 + r;
        int gcol = n0 + wn + ni * 16 + lr;
        float val = acc[mi][ni][r];
        if constexpr (MODE == 1) val = fmaxf(val, 0.f);
        if constexpr (MODE == 0 || MODE == 1) {
          ((unsigned short*)outp)[(size_t)grow * N + gcol] = f2bf(val);
        } else if constexpr (MODE == 2) {
          ((float*)outp)[(size_t)grow * N + gcol] =
              resid[(size_t)grow * N + gcol] + val;
        } else if constexpr (MODE == 3) {
          int which = gcol >> 10, hh = (gcol >> 6) & 15, dd = gcol & 63;
          int b = grow >> 10, t = grow & 1023;
          unsigned short hv = f2bf(val);
          size_t bh = (size_t)(b * 16 + hh) << 16;
          if (which == 0)      qo[bh + t * 64 + dd] = hv;
          else if (which == 1) ko[bh + t * 64 + dd] = hv;
          else                 vo[bh + dd * 1024 + t] = hv;
        } else {
          if (gcol < N)
            ((float*)outp)[(size_t)grow * (size_t)N + gcol] = val;
        }
      }
}

// ---------------- 128x64 ring-4 counted-vmcnt NT GEMM (narrow N) ----------------
// 48 KiB LDS -> 3 blocks/CU (144 <= 160 KiB); __launch_bounds__(256,3)
// declares it (VGPR 3x88=264 <= 512/SIMD pool, no regalloc pressure).
// qkv grid 768 = exactly 3/CU -> 12 waves/CU of cross-block MFMA overlap.
template <int MODE>
__global__ __launch_bounds__(256, 3) void gemm64n_bt(
    const unsigned short* __restrict__ A, const unsigned short* __restrict__ Wb,
    void* __restrict__ outp, const float* __restrict__ resid,
    unsigned short* __restrict__ qo, unsigned short* __restrict__ ko,
    unsigned short* __restrict__ vo, int M, int N, int K) {
  __shared__ unsigned short As[4][128 * 32];
  __shared__ unsigned short Bs[4][64 * 32];

  const int tid = threadIdx.x;
  const int lane = tid & 63;
  const int wv = tid >> 6;
  const int lr = lane & 15, lh = lane >> 4;
  const int nbm = M >> 7;
  const int nb = gridDim.x;
  const int bid = blockIdx.x;
  const int swz = (bid & 7) * (nb >> 3) + (bid >> 3);   // bijective XCD chunking
  const int m0 = (swz % nbm) << 7;
  const int n0 = (swz / nbm) << 6;
  const int wm = (wv >> 1) << 6;
  const int wn = (wv & 1) << 5;
  const int nK = K >> 5;

  size_t aoff[2], boff;
  int ldsta[2], ldstb;
#pragma unroll
  for (int j = 0; j < 2; ++j) {
    int u = j * 256 + tid;              // A: 512 lane-loads (64 phys rows)
    int p = u >> 3, s = u & 7;
    int ss = s ^ (p & 7);
    int arow = m0 + 2 * p + (ss >> 2);
    aoff[j] = (size_t)arow * K + (ss & 3) * 8;
    ldsta[j] = u * 16;
  }
  {
    int u = tid;                        // B: 256 lane-loads (32 phys rows)
    int p = u >> 3, s = u & 7;
    int ss = s ^ (p & 7);
    int brow = n0 + 2 * p + (ss >> 2);
    if (brow >= N) brow = N - 1;
    boff = (size_t)brow * K + (ss & 3) * 8;
    ldstb = u * 16;
  }

  auto stage = [&](int buf, int k) {
#pragma unroll
    for (int j = 0; j < 2; ++j)
      gload16(A + aoff[j] + k * 32, (char*)(&As[buf][0]) + ldsta[j]);
    gload16(Wb + boff + k * 32, (char*)(&Bs[buf][0]) + ldstb);
  };

  f32x4 acc[4][2];
#pragma unroll
  for (int a = 0; a < 4; ++a)
#pragma unroll
    for (int b = 0; b < 2; ++b) acc[a][b] = f32x4{0.f, 0.f, 0.f, 0.f};

  stage(0, 0);
  if (nK > 1) stage(1, 1);
  if (nK > 2) stage(2, 2);
  if (nK > 2)      asm volatile("s_waitcnt vmcnt(6)" ::: "memory");
  else if (nK > 1) asm volatile("s_waitcnt vmcnt(3)" ::: "memory");
  else             asm volatile("s_waitcnt vmcnt(0)" ::: "memory");
  __builtin_amdgcn_s_barrier();
  __builtin_amdgcn_sched_barrier(0);

  for (int kt = 0; kt < nK; ++kt) {
    const int buf = kt & 3;
    bf16x8 af[4], bfr[2];
#pragma unroll
    for (int ni = 0; ni < 2; ++ni) {
      int r = wn + ni * 16 + lr;
      int p = r >> 1;
      int off = p * 128 + (((((r & 1) << 2) | lh) ^ (p & 7)) << 4);
      bfr[ni] = *(const bf16x8*)((const char*)(&Bs[buf][0]) + off);
    }
#pragma unroll
    for (int mi = 0; mi < 4; ++mi) {
      int r = wm + mi * 16 + lr;
      int p = r >> 1;
      int off = p * 128 + (((((r & 1) << 2) | lh) ^ (p & 7)) << 4);
      af[mi] = *(const bf16x8*)((const char*)(&As[buf][0]) + off);
    }
    if (kt + 3 < nK) stage((kt + 3) & 3, kt + 3);

    __builtin_amdgcn_s_setprio(1);
#pragma unroll
    for (int mi = 0; mi < 4; ++mi)
#pragma unroll
      for (int ni = 0; ni < 2; ++ni)
        acc[mi][ni] = __builtin_amdgcn_mfma_f32_16x16x32_bf16(
            af[mi], bfr[ni], acc[mi][ni], 0, 0, 0);
    __builtin_amdgcn_s_setprio(0);

    if (kt + 1 < nK) {
      if (kt + 4 <= nK)      asm volatile("s_waitcnt vmcnt(6)" ::: "memory");
      else if (kt + 3 <= nK) asm volatile("s_waitcnt vmcnt(3)" ::: "memory");
      else                   asm volatile("s_waitcnt vmcnt(0)" ::: "memory");
      __builtin_amdgcn_s_barrier();
      __builtin_amdgcn_sched_barrier(0);
    }
  }

  // epilogue
#pragma unroll
  for (int mi = 0; mi < 4; ++mi)
#pragma unroll
    for (int ni = 0; ni < 2; ++ni)
#pragma unroll
      for (int r = 0; r < 4; ++r) {
        int grow = m0 + wm + mi * 16 + lh * 4 + r;
        int gcol = n0 + wn + ni * 16 + lr;
        float val = acc[mi][ni][r];
        if constexpr (MODE == 1) val = fmaxf(val, 0.f);
        if constexpr (MODE == 0 || MODE == 1) {
          ((unsigned short*)outp)[(size_t)grow * N + gcol] = f2bf(val);
        } else if constexpr (MODE == 2) {
          ((float*)outp)[(size_t)grow * N + gcol] =
              resid[(size_t)grow * N + gcol] + val;
        } else if constexpr (MODE == 3) {
          int which = gcol >> 10, hh = (gcol >> 6) & 15, dd = gcol & 63;
          int b = grow >> 10, t = grow & 1023;
          unsigned short hv = f2bf(val);
          size_t bh = (size_t)(b * 16 + hh) << 16;
          if (which == 0)      qo[bh + t * 64 + dd] = hv;
          else if (which == 1) ko[bh + t * 64 + dd] = hv;
          else                 vo[bh + dd * 1024 + t] = hv;
        } else {
          if (gcol < N)
            ((float*)outp)[(size_t)grow * (size_t)N + gcol] = val;
        }
      }
}

// ---------------- 256x256 ring-4 deep-pipelined NT GEMM (head, proven) ------
__global__ __launch_bounds__(512, 2) void gemm256_bt(
    const unsigned short* __restrict__ A, const unsigned short* __restrict__ Wb,
    float* __restrict__ out, int M, int N, int K) {
  __shared__ unsigned short As[4][256 * 32];
  __shared__ unsigned short Bs[4][256 * 32];

  const int tid = threadIdx.x;
  const int lane = tid & 63;
  const int wv = tid >> 6;
  const int lr = lane & 15, lh = lane >> 4;
  const int wm = (wv >> 2) * 128;   // warp_m in {0,1}
  const int wn = (wv & 3) * 64;     // warp_n in {0..3}
  const int nbm = M >> 8;
  const int nb = gridDim.x;
  const int bid = blockIdx.x;
  const int swz = (bid & 7) * (nb >> 3) + (bid >> 3);  // bijective XCD chunking
  const int m0 = (swz % nbm) << 8;
  const int n0 = (swz / nbm) << 8;
  const int nK = K >> 5;

  size_t aoff[2], boff[2];
  int ldst[2];
#pragma unroll
  for (int j = 0; j < 2; ++j) {
    int u = j * 512 + tid;
    int p = u >> 3, s = u & 7;
    int ss = s ^ (p & 7);            // inverse swizzle on the source side
    int arow = m0 + 2 * p + (ss >> 2);
    int brow = n0 + 2 * p + (ss >> 2);
    if (brow >= N) brow = N - 1;
    aoff[j] = (size_t)arow * K + (ss & 3) * 8;
    boff[j] = (size_t)brow * K + (ss & 3) * 8;
    ldst[j] = u * 16;
  }

  auto stage = [&](int buf, int k) {
#pragma unroll
    for (int j = 0; j < 2; ++j)
      gload16(A + aoff[j] + k * 32, (char*)(&As[buf][0]) + ldst[j]);
#pragma unroll
    for (int j = 0; j < 2; ++j)
      gload16(Wb + boff[j] + k * 32, (char*)(&Bs[buf][0]) + ldst[j]);
  };

  f32x4 acc[8][4];
#pragma unroll
  for (int a = 0; a < 8; ++a)
#pragma unroll
    for (int b = 0; b < 4; ++b) acc[a][b] = f32x4{0.f, 0.f, 0.f, 0.f};

  stage(0, 0);
  if (nK > 1) stage(1, 1);
  if (nK > 2) stage(2, 2);
  if (nK > 2) asm volatile("s_waitcnt vmcnt(8)" ::: "memory");
  else        asm volatile("s_waitcnt vmcnt(0)" ::: "memory");
  __builtin_amdgcn_s_barrier();
  __builtin_amdgcn_sched_barrier(0);

  for (int k = 0; k < nK; ++k) {
    const int buf = k & 3;
    bf16x8 af[8], bfr[4];
#pragma unroll
    for (int ni = 0; ni < 4; ++ni) {
      int r = wn + ni * 16 + lr;
      int p = r >> 1;
      int off = p * 128 + (((((r & 1) << 2) | lh) ^ (p & 7)) << 4);
      bfr[ni] = *(const bf16x8*)((const char*)(&Bs[buf][0]) + off);
    }
#pragma unroll
    for (int mi = 0; mi < 8; ++mi) {
      int r = wm + mi * 16 + lr;
      int p = r >> 1;
      int off = p * 128 + (((((r & 1) << 2) | lh) ^ (p & 7)) << 4);
      af[mi] = *(const bf16x8*)((const char*)(&As[buf][0]) + off);
    }
    if (k + 3 < nK) stage((k + 3) & 3, k + 3);

    __builtin_amdgcn_s_setprio(1);
#pragma unroll
    for (int mi = 0; mi < 8; ++mi)
#pragma unroll
      for (int ni = 0; ni < 4; ++ni)
        acc[mi][ni] = __builtin_amdgcn_mfma_f32_16x16x32_bf16(
            af[mi], bfr[ni], acc[mi][ni], 0, 0, 0);
    __builtin_amdgcn_s_setprio(0);

    if (k + 1 < nK) {
      if (k + 4 <= nK)      asm volatile("s_waitcnt vmcnt(8)" ::: "memory");
      else if (k + 3 <= nK) asm volatile("s_waitcnt vmcnt(4)" ::: "memory");
      else                  asm volatile("s_waitcnt vmcnt(0)" ::: "memory");
      __builtin_amdgcn_s_barrier();
      __builtin_amdgcn_sched_barrier(0);
    }
  }

#pragma unroll
  for (int mi = 0; mi < 8; ++mi)
#pragma unroll
    for (int ni = 0; ni < 4; ++ni)
#pragma unroll
      for (int r = 0; r < 4; ++r) {
        int grow = m0 + wm + mi * 16 + lh * 4 + r;
        int gcol = n0 + wn + ni * 16 + lr;
        if (gcol < N) out[(size_t)grow * (size_t)N + gcol] = acc[mi][ni][r];
      }
}

// ---------------- flash attention, causal-balanced, 2 waves/block -------------
__global__ __launch_bounds__(128, 2) void attn_kernel(
    const unsigned short* __restrict__ qb, const unsigned short* __restrict__ kb,
    const unsigned short* __restrict__ vt, unsigned short* __restrict__ yb) {
  __shared__ unsigned short Ks[2][64 * 64];
  __shared__ unsigned short Vs[2][64 * 64];
  __shared__ unsigned short Ps[2][32 * 64];

  const int tid = threadIdx.x, lane = tid & 63, wv = tid >> 6;
  const int lr = lane & 15, lh = lane >> 4;
  const int bid = blockIdx.x;
  const int bh = bid & 31;
  const int rest = bid >> 5;
  const int j = rest >> 1, hf = rest & 1;
  const int sub = (hf * 2 + wv) * 16;
  const int rb0 = j * 64 + sub;              // chunk A rows (mi=0)
  const int rb1 = (15 - j) * 64 + sub;       // chunk B rows (mi=1)
  const unsigned short* qp = qb + ((size_t)bh << 16);
  const unsigned short* kp = kb + ((size_t)bh << 16);
  const unsigned short* vp = vt + ((size_t)bh << 16);

  bf16x8 qf[2][2];
#pragma unroll
  for (int mi = 0; mi < 2; ++mi)
#pragma unroll
    for (int ks = 0; ks < 2; ++ks) {
      int row = (mi ? rb1 : rb0) + lr;
      qf[mi][ks] = *(const bf16x8*)(qp + (size_t)row * 64 + ks * 32 + lh * 8);
    }

  f32x4 o[2][4];
  float mr[2][4], lsum[2][4];
#pragma unroll
  for (int mi = 0; mi < 2; ++mi) {
#pragma unroll
    for (int di = 0; di < 4; ++di) o[mi][di] = f32x4{0.f, 0.f, 0.f, 0.f};
#pragma unroll
    for (int r = 0; r < 4; ++r) { mr[mi][r] = -1e30f; lsum[mi][r] = 0.f; }
  }

  const int ntiles = 16 - j;

  auto stageKV = [&](int buf, int t) {
    int kv0 = t << 6;
#pragma unroll
    for (int jj = 0; jj < 4; ++jj) {
      int u = jj * 128 + tid;
      int row = u >> 3, un = u & 7;
      gload16(kp + (size_t)(kv0 + row) * 64 + ((un ^ (row & 7)) << 3),
              (char*)(&Ks[buf][0]) + u * 16);
      gload16(vp + (size_t)row * 1024 + kv0 + ((un ^ (row & 7)) << 3),
              (char*)(&Vs[buf][0]) + u * 16);
    }
  };

  stageKV(0, 0);

  for (int t = 0; t < ntiles; ++t) {
    __syncthreads();
    if (t + 1 < ntiles) stageKV((t + 1) & 1, t + 1);
    int cur = t & 1;
    int kv0 = t << 6;
    const bool act0 = (t <= j);   // chunk A active this tile (block-uniform)

    f32x4 s[2][4];
#pragma unroll
    for (int mi = 0; mi < 2; ++mi)
#pragma unroll
      for (int ni = 0; ni < 4; ++ni) s[mi][ni] = f32x4{0.f, 0.f, 0.f, 0.f};

    bf16x8 kf[4][2];
#pragma unroll
    for (int ni = 0; ni < 4; ++ni)
#pragma unroll
      for (int ks = 0; ks < 2; ++ks) {
        int row = ni * 16 + lr;
        int off = row * 128 + ((ks * 64 + lh * 16) ^ ((row & 7) << 4));
        kf[ni][ks] = *(const bf16x8*)((const char*)(&Ks[cur][0]) + off);
      }
#pragma unroll
    for (int ks = 0; ks < 2; ++ks)
#pragma unroll
      for (int ni = 0; ni < 4; ++ni) {
        if (act0)
          s[0][ni] = __builtin_amdgcn_mfma_f32_16x16x32_bf16(
              qf[0][ks], kf[ni][ks], s[0][ni], 0, 0, 0);
        s[1][ni] = __builtin_amdgcn_mfma_f32_16x16x32_bf16(
            qf[1][ks], kf[ni][ks], s[1][ni], 0, 0, 0);
      }

    // scale + causal mask + online softmax (per mi; mi=0 gated)
#pragma unroll
    for (int mi = 0; mi < 2; ++mi) {
      if (mi == 0 && !act0) continue;
      const int rb = mi ? rb1 : rb0;
#pragma unroll
      for (int r = 0; r < 4; ++r) {
        int rowq = rb + lh * 4 + r;
        float xv[4];
        float pm = -1e30f;
#pragma unroll
        for (int ni = 0; ni < 4; ++ni) {
          int col = kv0 + ni * 16 + lr;
          float xx = s[mi][ni][r] * 0.125f;
          if (col > rowq) xx = -1e30f;
          xv[ni] = xx;
          pm = fmaxf(pm, xx);
        }
#pragma unroll
        for (int msk = 1; msk < 16; msk <<= 1)
          pm = fmaxf(pm, __shfl_xor(pm, msk, 64));
        float mnew = fmaxf(mr[mi][r], pm);
        float al = exp2f((mr[mi][r] - mnew) * LOG2E);
        mr[mi][r] = mnew;
        float ps = 0.f;
#pragma unroll
        for (int ni = 0; ni < 4; ++ni) {
          float p = exp2f((xv[ni] - mnew) * LOG2E);
          s[mi][ni][r] = p;
          ps += p;
        }
#pragma unroll
        for (int msk = 1; msk < 16; msk <<= 1) ps += __shfl_xor(ps, msk, 64);
        lsum[mi][r] = lsum[mi][r] * al + ps;
#pragma unroll
        for (int di = 0; di < 4; ++di) o[mi][di][r] *= al;
      }
    }

    // P (C-layout) -> per-wave LDS (A-frag layout), swizzled; mi=0 gated
#pragma unroll
    for (int mi = 0; mi < 2; ++mi) {
      if (mi == 0 && !act0) continue;
#pragma unroll
      for (int ni = 0; ni < 4; ++ni)
#pragma unroll
        for (int r = 0; r < 4; ++r) {
          int row = mi * 16 + lh * 4 + r;
          int off = row * 128 + (((ni * 16 + lr) * 2) ^ ((row & 7) << 4));
          *(unsigned short*)((char*)(&Ps[wv][0]) + off) = f2bf(s[mi][ni][r]);
        }
    }

    bf16x8 pf[2][2], vf[4][2];
#pragma unroll
    for (int mi = 0; mi < 2; ++mi) {
      if (mi == 0 && !act0) continue;
#pragma unroll
      for (int ks = 0; ks < 2; ++ks) {
        int row = mi * 16 + lr;
        int off = row * 128 + ((ks * 64 + lh * 16) ^ ((row & 7) << 4));
        pf[mi][ks] = *(const bf16x8*)((const char*)(&Ps[wv][0]) + off);
      }
    }
#pragma unroll
    for (int di = 0; di < 4; ++di)
#pragma unroll
      for (int ks = 0; ks < 2; ++ks) {
        int row = di * 16 + lr;
        int off = row * 128 + ((ks * 64 + lh * 16) ^ ((row & 7) << 4));
        vf[di][ks] = *(const bf16x8*)((const char*)(&Vs[cur][0]) + off);
      }
#pragma unroll
    for (int ks = 0; ks < 2; ++ks)
#pragma unroll
      for (int di = 0; di < 4; ++di) {
        if (act0)
          o[0][di] = __builtin_amdgcn_mfma_f32_16x16x32_bf16(
              pf[0][ks], vf[di][ks], o[0][di], 0, 0, 0);
        o[1][di] = __builtin_amdgcn_mfma_f32_16x16x32_bf16(
            pf[1][ks], vf[di][ks], o[1][di], 0, 0, 0);
      }
  }

  int b = bh >> 4, hh = bh & 15;
#pragma unroll
  for (int mi = 0; mi < 2; ++mi)
#pragma unroll
    for (int r = 0; r < 4; ++r) {
      float inv = 1.f / lsum[mi][r];
      int rowq = (mi ? rb1 : rb0) + lh * 4 + r;
      size_t mg = (size_t)(b * 1024 + rowq) * 1024 + hh * 64;
#pragma unroll
      for (int di = 0; di < 4; ++di)
        yb[mg + di * 16 + lr] = f2bf(o[mi][di][r] * inv);
    }
}

// ---------------- launch ----------------
extern "C" void kernel_launch(void* const* d_in, const int* in_sizes, int n_in,
                              void* d_out, int out_size, void* d_ws,
                              size_t ws_size, hipStream_t stream) {
  const int*   idx  = (const int*)d_in[0];
  const float* wte  = (const float*)d_in[1];
  const float* wpe  = (const float*)d_in[2];
  const float* ln1w = (const float*)d_in[3];
  const float* attnw= (const float*)d_in[4];
  const float* aprj = (const float*)d_in[5];
  const float* ln2w = (const float*)d_in[6];
  const float* fcw  = (const float*)d_in[7];
  const float* mprj = (const float*)d_in[8];
  const float* lnfw = (const float*)d_in[9];
  const float* hw   = (const float*)d_in[10];
  float* out = (float*)d_out;
  char* ws = (char*)d_ws;

  float* x            = (float*)ws;                                  // 8 MB
  unsigned short* h   = (unsigned short*)(ws + ((size_t)8 << 20));   // 4 MB
  unsigned short* qbf = (unsigned short*)(ws + ((size_t)12 << 20));  // 4 MB
  unsigned short* kbf = (unsigned short*)(ws + ((size_t)16 << 20));  // 4 MB
  unsigned short* vtb = (unsigned short*)(ws + ((size_t)20 << 20));  // 4 MB
  unsigned short* ybf = (unsigned short*)(ws + ((size_t)24 << 20));  // 4 MB
  unsigned short* mhb = (unsigned short*)(ws + ((size_t)12 << 20));  // 16 MB, aliases qkv/y (safe by schedule)

  // bf16 weight copies
  size_t off = (size_t)28 << 20;
  unsigned short* attnw16 = (unsigned short*)(ws + off); off += (size_t)4 * 3072 * 1024 * 2;
  unsigned short* aprj16  = (unsigned short*)(ws + off); off += (size_t)4 * 1024 * 1024 * 2;
  unsigned short* fcw16   = (unsigned short*)(ws + off); off += (size_t)4 * 4096 * 1024 * 2;
  unsigned short* mprj16  = (unsigned short*)(ws + off); off += (size_t)4 * 1024 * 4096 * 2;
  unsigned short* hw16    = (unsigned short*)(ws + off); off += (size_t)50257 * 1024 * 2;
  const bool b16 = ws_size >= off;

  embed_kernel<<<2048, 256, 0, stream>>>(idx, wte, wpe, x);

  if (b16) {
    cvt5_kernel<<<2048, 256, 0, stream>>>(
        attnw, attnw16, 4 * 3072 * 1024 / 8,
        aprj,  aprj16,  4 * 1024 * 1024 / 8,
        fcw,   fcw16,   4 * 4096 * 1024 / 8,
        mprj,  mprj16,  4 * 1024 * 4096 / 8,
        hw,    hw16,    50257 * 1024 / 8);
  }

  for (int l = 0; l < 4; ++l) {
    ln_kernel<<<2048, 256, 0, stream>>>(x, ln1w + l * 1024, h);
    if (b16)
      gemm64n_bt<3><<<16 * 48, 256, 0, stream>>>(
          h, attnw16 + (size_t)l * 3072 * 1024, nullptr, nullptr, qbf, kbf,
          vtb, 2048, 3072, 1024);
    else
      gemm_bt<3, false><<<16 * 24, 256, 0, stream>>>(
          h, attnw + (size_t)l * 3072 * 1024, nullptr, nullptr, qbf, kbf, vtb,
          2048, 3072, 1024);
    attn_kernel<<<512, 128, 0, stream>>>(qbf, kbf, vtb, ybf);
    if (b16)
      gemm64n_bt<2><<<16 * 16, 256, 0, stream>>>(
          ybf, aprj16 + (size_t)l * 1024 * 1024, x, x, nullptr, nullptr,
          nullptr, 2048, 1024, 1024);
    else
      gemm_bt<2, false><<<16 * 8, 256, 0, stream>>>(
          ybf, aprj + (size_t)l * 1024 * 1024, x, x, nullptr, nullptr, nullptr,
          2048, 1024, 1024);
    ln_kernel<<<2048, 256, 0, stream>>>(x, ln2w + l * 1024, h);
    if (b16)
      gemm128_bt<1><<<16 * 32, 256, 0, stream>>>(
          h, fcw16 + (size_t)l * 4096 * 1024, mhb, nullptr, nullptr, nullptr,
          nullptr, 2048, 4096, 1024);
    else
      gemm_bt<1, false><<<16 * 32, 256, 0, stream>>>(
          h, fcw + (size_t)l * 4096 * 1024, mhb, nullptr, nullptr, nullptr,
          nullptr, 2048, 4096, 1024);
    if (b16)
      gemm64n_bt<2><<<16 * 16, 256, 0, stream>>>(
          mhb, mprj16 + (size_t)l * 1024 * 4096, x, x, nullptr, nullptr,
          nullptr, 2048, 1024, 4096);
    else
      gemm_bt<2, false><<<16 * 8, 256, 0, stream>>>(
          mhb, mprj + (size_t)l * 1024 * 4096, x, x, nullptr, nullptr, nullptr,
          2048, 1024, 4096);
  }

  ln_kernel<<<2048, 256, 0, stream>>>(x, lnfw, h);
  if (b16)
    gemm256_bt<<<8 * 197, 512, 0, stream>>>(h, hw16, out, 2048, 50257, 1024);
  else
    gemm_bt<4, false><<<16 * 393, 256, 0, stream>>>(
        h, hw, out, nullptr, nullptr, nullptr, nullptr, 2048, 50257, 1024);
}

// Round 10
// 1184.290 us; speedup vs baseline: 1.0745x; 1.0169x over previous
//
#include <hip/hip_runtime.h>

typedef __bf16 bf16x8 __attribute__((ext_vector_type(8)));
typedef float f32x4 __attribute__((ext_vector_type(4)));
typedef unsigned short u16x8 __attribute__((ext_vector_type(8)));

#define LOG2E 1.4426950408889634f

__device__ __forceinline__ unsigned short f2bf(float f) {
  union { float f; unsigned u; } v; v.f = f;
  return (unsigned short)((v.u + 0x7fffu + ((v.u >> 16) & 1u)) >> 16);
}

__device__ __forceinline__ void gload16(const void* g, void* l) {
  __builtin_amdgcn_global_load_lds(
      (const __attribute__((address_space(1))) unsigned int*)g,
      (__attribute__((address_space(3))) unsigned int*)l, 16, 0, 0);
}

// ---------------- weight f32 -> bf16 convert (5 segments, 1 launch) ---------
__global__ __launch_bounds__(256) void cvt5_kernel(
    const float* __restrict__ s0, unsigned short* __restrict__ d0, int n0,
    const float* __restrict__ s1, unsigned short* __restrict__ d1, int n1,
    const float* __restrict__ s2, unsigned short* __restrict__ d2, int n2,
    const float* __restrict__ s3, unsigned short* __restrict__ d3, int n3,
    const float* __restrict__ s4, unsigned short* __restrict__ d4, int n4) {
  int stride = gridDim.x * 256;
  const float* ss[5] = {s0, s1, s2, s3, s4};
  unsigned short* dd[5] = {d0, d1, d2, d3, d4};
  int nn[5] = {n0, n1, n2, n3, n4};
#pragma unroll
  for (int seg = 0; seg < 5; ++seg) {
    const float* s = ss[seg];
    unsigned short* d = dd[seg];
    int n8 = nn[seg];
    for (int i = blockIdx.x * 256 + threadIdx.x; i < n8; i += stride) {
      float4 a = ((const float4*)s)[2 * i];
      float4 b = ((const float4*)s)[2 * i + 1];
      u16x8 o;
      o[0] = f2bf(a.x); o[1] = f2bf(a.y); o[2] = f2bf(a.z); o[3] = f2bf(a.w);
      o[4] = f2bf(b.x); o[5] = f2bf(b.y); o[6] = f2bf(b.z); o[7] = f2bf(b.w);
      ((u16x8*)d)[i] = o;
    }
  }
}

// ---------------- embedding ----------------
__global__ __launch_bounds__(256) void embed_kernel(
    const int* __restrict__ idx, const float* __restrict__ wte,
    const float* __restrict__ wpe, float* __restrict__ x) {
  int row = blockIdx.x;            // 0..2047  (b*1024 + t)
  int tok = idx[row];
  int t = row & 1023;
  float4 a = ((const float4*)(wte + (size_t)tok * 1024))[threadIdx.x];
  float4 p = ((const float4*)(wpe + (size_t)t * 1024))[threadIdx.x];
  a.x += p.x; a.y += p.y; a.z += p.z; a.w += p.w;
  ((float4*)(x + (size_t)row * 1024))[threadIdx.x] = a;
}

// ---------------- layernorm (block per row, C=1024) ----------------
__global__ __launch_bounds__(256) void ln_kernel(
    const float* __restrict__ x, const float* __restrict__ w,
    unsigned short* __restrict__ out) {
  __shared__ float2 red[4];
  int row = blockIdx.x, tid = threadIdx.x;
  float4 v = ((const float4*)(x + (size_t)row * 1024))[tid];
  float s  = v.x + v.y + v.z + v.w;
  float s2 = v.x * v.x + v.y * v.y + v.z * v.z + v.w * v.w;
#pragma unroll
  for (int m = 32; m >= 1; m >>= 1) {
    s  += __shfl_xor(s, m, 64);
    s2 += __shfl_xor(s2, m, 64);
  }
  if ((tid & 63) == 0) red[tid >> 6] = make_float2(s, s2);
  __syncthreads();
  float S = 0.f, S2 = 0.f;
#pragma unroll
  for (int i = 0; i < 4; ++i) { S += red[i].x; S2 += red[i].y; }
  float mu = S * (1.f / 1024.f);
  float var = S2 * (1.f / 1024.f) - mu * mu;
  float rs = rsqrtf(var + 1e-5f);
  float4 wv = ((const float4*)w)[tid];
  ushort4 o;
  o.x = f2bf((v.x - mu) * rs * wv.x);
  o.y = f2bf((v.y - mu) * rs * wv.y);
  o.z = f2bf((v.z - mu) * rs * wv.z);
  o.w = f2bf((v.w - mu) * rs * wv.w);
  ((ushort4*)(out + (size_t)row * 1024))[tid] = o;
}

// ---------------- OLD NT GEMM (f32-weight fallback only) ----------------
template <int MODE, bool WB16>
__global__ __launch_bounds__(256, 2) void gemm_bt(
    const unsigned short* __restrict__ A, const void* __restrict__ Wp,
    void* __restrict__ outp, const float* __restrict__ resid,
    unsigned short* __restrict__ qo, unsigned short* __restrict__ ko,
    unsigned short* __restrict__ vo, int M, int N, int K) {
  __shared__ unsigned short As[2][128 * 64];
  __shared__ unsigned short Bs[2][128 * 64];

  const int tid = threadIdx.x;
  const int lane = tid & 63;
  const int wv = tid >> 6;
  const int lr = lane & 15, lh = lane >> 4;
  const int nbm = M >> 7;
  const int nb = gridDim.x;
  const int bid = blockIdx.x;
  const int swz = (bid & 7) * (nb >> 3) + (bid >> 3);   // bijective XCD chunking
  const int m0 = (swz % nbm) << 7;
  const int n0 = (swz / nbm) << 7;
  const int wm = (wv >> 1) << 6;
  const int wn = (wv & 1) << 6;
  const int nK = K >> 6;

  float4 breg[8];
  const float* Wf = (const float*)Wp;
  const unsigned short* Wb = (const unsigned short*)Wp;

  auto loadB = [&](int kt) {
#pragma unroll
    for (int j = 0; j < 8; ++j) {
      int u = j * 256 + tid;
      int rn = n0 + (u >> 4);
      if (rn >= N) rn = N - 1;
      breg[j] = *(const float4*)(Wf + (size_t)rn * K + kt * 64 + (u & 15) * 4);
    }
  };
  auto writeB = [&](int buf) {
#pragma unroll
    for (int j = 0; j < 8; ++j) {
      int u = j * 256 + tid;
      int row = u >> 4, q = u & 15;
      ushort4 h4;
      h4.x = f2bf(breg[j].x); h4.y = f2bf(breg[j].y);
      h4.z = f2bf(breg[j].z); h4.w = f2bf(breg[j].w);
      int off = row * 128 + ((q * 8) ^ ((row & 7) << 4));
      *(ushort4*)((char*)(&Bs[buf][0]) + off) = h4;
    }
  };
  auto stageA = [&](int buf, int kt) {
    const unsigned short* base = A + (size_t)m0 * K + kt * 64;
#pragma unroll
    for (int j = 0; j < 4; ++j) {
      int u = j * 256 + tid;
      int row = u >> 3, un = u & 7;
      gload16(base + (size_t)row * K + ((un ^ (row & 7)) << 3),
              (char*)(&As[buf][0]) + u * 16);
    }
  };
  auto stageB16 = [&](int buf, int kt) {
#pragma unroll
    for (int j = 0; j < 4; ++j) {
      int u = j * 256 + tid;
      int row = u >> 3, un = u & 7;
      size_t grow = (size_t)(n0 + row);
      if constexpr (MODE == 4) { if ((int)grow >= N) grow = N - 1; }
      gload16(Wb + grow * K + kt * 64 + ((un ^ (row & 7)) << 3),
              (char*)(&Bs[buf][0]) + u * 16);
    }
  };

  f32x4 acc[4][4];
#pragma unroll
  for (int a = 0; a < 4; ++a)
#pragma unroll
    for (int b = 0; b < 4; ++b) acc[a][b] = f32x4{0.f, 0.f, 0.f, 0.f};

  if constexpr (WB16) {
    stageA(0, 0);
    stageB16(0, 0);
  } else {
    loadB(0);
    stageA(0, 0);
    writeB(0);
  }
  __syncthreads();

  for (int kt = 0; kt < nK; ++kt) {
    int cur = kt & 1;
    if constexpr (WB16) {
      if (kt + 1 < nK) { stageA(cur ^ 1, kt + 1); stageB16(cur ^ 1, kt + 1); }
    } else {
      if (kt + 1 < nK) { loadB(kt + 1); stageA(cur ^ 1, kt + 1); }
    }

    bf16x8 af[4][2], bf[4][2];
#pragma unroll
    for (int mi = 0; mi < 4; ++mi)
#pragma unroll
      for (int ks = 0; ks < 2; ++ks) {
        int row = wm + mi * 16 + lr;
        int off = row * 128 + ((ks * 64 + lh * 16) ^ ((row & 7) << 4));
        af[mi][ks] = *(const bf16x8*)((const char*)(&As[cur][0]) + off);
      }
#pragma unroll
    for (int ni = 0; ni < 4; ++ni)
#pragma unroll
      for (int ks = 0; ks < 2; ++ks) {
        int row = wn + ni * 16 + lr;
        int off = row * 128 + ((ks * 64 + lh * 16) ^ ((row & 7) << 4));
        bf[ni][ks] = *(const bf16x8*)((const char*)(&Bs[cur][0]) + off);
      }
#pragma unroll
    for (int ks = 0; ks < 2; ++ks)
#pragma unroll
      for (int mi = 0; mi < 4; ++mi)
#pragma unroll
        for (int ni = 0; ni < 4; ++ni)
          acc[mi][ni] = __builtin_amdgcn_mfma_f32_16x16x32_bf16(
              af[mi][ks], bf[ni][ks], acc[mi][ni], 0, 0, 0);

    if constexpr (!WB16) {
      if (kt + 1 < nK) writeB(cur ^ 1);
    }
    __syncthreads();
  }

#pragma unroll
  for (int mi = 0; mi < 4; ++mi)
#pragma unroll
    for (int ni = 0; ni < 4; ++ni)
#pragma unroll
      for (int r = 0; r < 4; ++r) {
        int grow = m0 + wm + mi * 16 + lh * 4 + r;
        int gcol = n0 + wn + ni * 16 + lr;
        float val = acc[mi][ni][r];
        if constexpr (MODE == 1) val = fmaxf(val, 0.f);
        if constexpr (MODE == 0 || MODE == 1) {
          ((unsigned short*)outp)[(size_t)grow * N + gcol] = f2bf(val);
        } else if constexpr (MODE == 2) {
          ((float*)outp)[(size_t)grow * N + gcol] =
              resid[(size_t)grow * N + gcol] + val;
        } else if constexpr (MODE == 3) {
          int which = gcol >> 10, hh = (gcol >> 6) & 15, dd = gcol & 63;
          int b = grow >> 10, t = grow & 1023;
          unsigned short hv = f2bf(val);
          size_t bh = (size_t)(b * 16 + hh) << 16;
          if (which == 0)      qo[bh + t * 64 + dd] = hv;
          else if (which == 1) ko[bh + t * 64 + dd] = hv;
          else                 vo[bh + dd * 1024 + t] = hv;
        } else {
          if (gcol < N)
            ((float*)outp)[(size_t)grow * (size_t)N + gcol] = val;
        }
      }
}

// ---------------- 128x128 ring-4 counted-vmcnt NT GEMM (bf16 W) ----------------
template <int MODE>
__global__ __launch_bounds__(256, 2) void gemm128_bt(
    const unsigned short* __restrict__ A, const unsigned short* __restrict__ Wb,
    void* __restrict__ outp, const float* __restrict__ resid,
    unsigned short* __restrict__ qo, unsigned short* __restrict__ ko,
    unsigned short* __restrict__ vo, int M, int N, int K) {
  __shared__ unsigned short As[4][128 * 32];
  __shared__ unsigned short Bs[4][128 * 32];

  const int tid = threadIdx.x;
  const int lane = tid & 63;
  const int wv = tid >> 6;
  const int lr = lane & 15, lh = lane >> 4;
  const int nbm = M >> 7;
  const int nb = gridDim.x;
  const int bid = blockIdx.x;
  const int swz = (bid & 7) * (nb >> 3) + (bid >> 3);   // bijective XCD chunking
  const int m0 = (swz % nbm) << 7;
  const int n0 = (swz / nbm) << 7;
  const int wm = (wv >> 1) << 6;
  const int wn = (wv & 1) << 6;
  const int nK = K >> 5;

  size_t aoff[2], boff[2];
  int ldst[2];
#pragma unroll
  for (int j = 0; j < 2; ++j) {
    int u = j * 256 + tid;              // 0..511 lane-loads, 16 B each
    int p = u >> 3, s = u & 7;          // 64 physical rows x 8 slots
    int ss = s ^ (p & 7);
    int arow = m0 + 2 * p + (ss >> 2);
    int brow = n0 + 2 * p + (ss >> 2);
    if (brow >= N) brow = N - 1;
    aoff[j] = (size_t)arow * K + (ss & 3) * 8;
    boff[j] = (size_t)brow * K + (ss & 3) * 8;
    ldst[j] = u * 16;
  }

  auto stage = [&](int buf, int k) {
#pragma unroll
    for (int j = 0; j < 2; ++j)
      gload16(A + aoff[j] + k * 32, (char*)(&As[buf][0]) + ldst[j]);
#pragma unroll
    for (int j = 0; j < 2; ++j)
      gload16(Wb + boff[j] + k * 32, (char*)(&Bs[buf][0]) + ldst[j]);
  };

  f32x4 acc[4][4];
#pragma unroll
  for (int a = 0; a < 4; ++a)
#pragma unroll
    for (int b = 0; b < 4; ++b) acc[a][b] = f32x4{0.f, 0.f, 0.f, 0.f};

  stage(0, 0);
  if (nK > 1) stage(1, 1);
  if (nK > 2) stage(2, 2);
  if (nK > 2)      asm volatile("s_waitcnt vmcnt(8)" ::: "memory");
  else if (nK > 1) asm volatile("s_waitcnt vmcnt(4)" ::: "memory");
  else             asm volatile("s_waitcnt vmcnt(0)" ::: "memory");
  __builtin_amdgcn_s_barrier();
  __builtin_amdgcn_sched_barrier(0);

  for (int kt = 0; kt < nK; ++kt) {
    const int buf = kt & 3;
    bf16x8 af[4], bfr[4];
#pragma unroll
    for (int ni = 0; ni < 4; ++ni) {
      int r = wn + ni * 16 + lr;
      int p = r >> 1;
      int off = p * 128 + (((((r & 1) << 2) | lh) ^ (p & 7)) << 4);
      bfr[ni] = *(const bf16x8*)((const char*)(&Bs[buf][0]) + off);
    }
#pragma unroll
    for (int mi = 0; mi < 4; ++mi) {
      int r = wm + mi * 16 + lr;
      int p = r >> 1;
      int off = p * 128 + (((((r & 1) << 2) | lh) ^ (p & 7)) << 4);
      af[mi] = *(const bf16x8*)((const char*)(&As[buf][0]) + off);
    }
    if (kt + 3 < nK) stage((kt + 3) & 3, kt + 3);

    __builtin_amdgcn_s_setprio(1);
#pragma unroll
    for (int mi = 0; mi < 4; ++mi)
#pragma unroll
      for (int ni = 0; ni < 4; ++ni)
        acc[mi][ni] = __builtin_amdgcn_mfma_f32_16x16x32_bf16(
            af[mi], bfr[ni], acc[mi][ni], 0, 0, 0);
    __builtin_amdgcn_s_setprio(0);

    if (kt + 1 < nK) {
      if (kt + 4 <= nK)      asm volatile("s_waitcnt vmcnt(8)" ::: "memory");
      else if (kt + 3 <= nK) asm volatile("s_waitcnt vmcnt(4)" ::: "memory");
      else                   asm volatile("s_waitcnt vmcnt(0)" ::: "memory");
      __builtin_amdgcn_s_barrier();
      __builtin_amdgcn_sched_barrier(0);
    }
  }

  // epilogue
#pragma unroll
  for (int mi = 0; mi < 4; ++mi)
#pragma unroll
    for (int ni = 0; ni < 4; ++ni)
#pragma unroll
      for (int r = 0; r < 4; ++r) {
        int grow = m0 + wm + mi * 16 + lh * 4 + r;
        int gcol = n0 + wn + ni * 16 + lr;
        float val = acc[mi][ni][r];
        if constexpr (MODE == 1) val = fmaxf(val, 0.f);
        if constexpr (MODE == 0 || MODE == 1) {
          ((unsigned short*)outp)[(size_t)grow * N + gcol] = f2bf(val);
        } else if constexpr (MODE == 2) {
          ((float*)outp)[(size_t)grow * N + gcol] =
              resid[(size_t)grow * N + gcol] + val;
        } else if constexpr (MODE == 3) {
          int which = gcol >> 10, hh = (gcol >> 6) & 15, dd = gcol & 63;
          int b = grow >> 10, t = grow & 1023;
          unsigned short hv = f2bf(val);
          size_t bh = (size_t)(b * 16 + hh) << 16;
          if (which == 0)      qo[bh + t * 64 + dd] = hv;
          else if (which == 1) ko[bh + t * 64 + dd] = hv;
          else                 vo[bh + dd * 1024 + t] = hv;
        } else {
          if (gcol < N)
            ((float*)outp)[(size_t)grow * (size_t)N + gcol] = val;
        }
      }
}

// ---------------- 128x64 ring-4 counted-vmcnt NT GEMM (narrow N) ----------------
template <int MODE>
__global__ __launch_bounds__(256, 3) void gemm64n_bt(
    const unsigned short* __restrict__ A, const unsigned short* __restrict__ Wb,
    void* __restrict__ outp, const float* __restrict__ resid,
    unsigned short* __restrict__ qo, unsigned short* __restrict__ ko,
    unsigned short* __restrict__ vo, int M, int N, int K) {
  __shared__ unsigned short As[4][128 * 32];
  __shared__ unsigned short Bs[4][64 * 32];

  const int tid = threadIdx.x;
  const int lane = tid & 63;
  const int wv = tid >> 6;
  const int lr = lane & 15, lh = lane >> 4;
  const int nbm = M >> 7;
  const int nb = gridDim.x;
  const int bid = blockIdx.x;
  const int swz = (bid & 7) * (nb >> 3) + (bid >> 3);   // bijective XCD chunking
  const int m0 = (swz % nbm) << 7;
  const int n0 = (swz / nbm) << 6;
  const int wm = (wv >> 1) << 6;
  const int wn = (wv & 1) << 5;
  const int nK = K >> 5;

  size_t aoff[2], boff;
  int ldsta[2], ldstb;
#pragma unroll
  for (int j = 0; j < 2; ++j) {
    int u = j * 256 + tid;              // A: 512 lane-loads (64 phys rows)
    int p = u >> 3, s = u & 7;
    int ss = s ^ (p & 7);
    int arow = m0 + 2 * p + (ss >> 2);
    aoff[j] = (size_t)arow * K + (ss & 3) * 8;
    ldsta[j] = u * 16;
  }
  {
    int u = tid;                        // B: 256 lane-loads (32 phys rows)
    int p = u >> 3, s = u & 7;
    int ss = s ^ (p & 7);
    int brow = n0 + 2 * p + (ss >> 2);
    if (brow >= N) brow = N - 1;
    boff = (size_t)brow * K + (ss & 3) * 8;
    ldstb = u * 16;
  }

  auto stage = [&](int buf, int k) {
#pragma unroll
    for (int j = 0; j < 2; ++j)
      gload16(A + aoff[j] + k * 32, (char*)(&As[buf][0]) + ldsta[j]);
    gload16(Wb + boff + k * 32, (char*)(&Bs[buf][0]) + ldstb);
  };

  f32x4 acc[4][2];
#pragma unroll
  for (int a = 0; a < 4; ++a)
#pragma unroll
    for (int b = 0; b < 2; ++b) acc[a][b] = f32x4{0.f, 0.f, 0.f, 0.f};

  stage(0, 0);
  if (nK > 1) stage(1, 1);
  if (nK > 2) stage(2, 2);
  if (nK > 2)      asm volatile("s_waitcnt vmcnt(6)" ::: "memory");
  else if (nK > 1) asm volatile("s_waitcnt vmcnt(3)" ::: "memory");
  else             asm volatile("s_waitcnt vmcnt(0)" ::: "memory");
  __builtin_amdgcn_s_barrier();
  __builtin_amdgcn_sched_barrier(0);

  for (int kt = 0; kt < nK; ++kt) {
    const int buf = kt & 3;
    bf16x8 af[4], bfr[2];
#pragma unroll
    for (int ni = 0; ni < 2; ++ni) {
      int r = wn + ni * 16 + lr;
      int p = r >> 1;
      int off = p * 128 + (((((r & 1) << 2) | lh) ^ (p & 7)) << 4);
      bfr[ni] = *(const bf16x8*)((const char*)(&Bs[buf][0]) + off);
    }
#pragma unroll
    for (int mi = 0; mi < 4; ++mi) {
      int r = wm + mi * 16 + lr;
      int p = r >> 1;
      int off = p * 128 + (((((r & 1) << 2) | lh) ^ (p & 7)) << 4);
      af[mi] = *(const bf16x8*)((const char*)(&As[buf][0]) + off);
    }
    if (kt + 3 < nK) stage((kt + 3) & 3, kt + 3);

    __builtin_amdgcn_s_setprio(1);
#pragma unroll
    for (int mi = 0; mi < 4; ++mi)
#pragma unroll
      for (int ni = 0; ni < 2; ++ni)
        acc[mi][ni] = __builtin_amdgcn_mfma_f32_16x16x32_bf16(
            af[mi], bfr[ni], acc[mi][ni], 0, 0, 0);
    __builtin_amdgcn_s_setprio(0);

    if (kt + 1 < nK) {
      if (kt + 4 <= nK)      asm volatile("s_waitcnt vmcnt(6)" ::: "memory");
      else if (kt + 3 <= nK) asm volatile("s_waitcnt vmcnt(3)" ::: "memory");
      else                   asm volatile("s_waitcnt vmcnt(0)" ::: "memory");
      __builtin_amdgcn_s_barrier();
      __builtin_amdgcn_sched_barrier(0);
    }
  }

  // epilogue
#pragma unroll
  for (int mi = 0; mi < 4; ++mi)
#pragma unroll
    for (int ni = 0; ni < 2; ++ni)
#pragma unroll
      for (int r = 0; r < 4; ++r) {
        int grow = m0 + wm + mi * 16 + lh * 4 + r;
        int gcol = n0 + wn + ni * 16 + lr;
        float val = acc[mi][ni][r];
        if constexpr (MODE == 1) val = fmaxf(val, 0.f);
        if constexpr (MODE == 0 || MODE == 1) {
          ((unsigned short*)outp)[(size_t)grow * N + gcol] = f2bf(val);
        } else if constexpr (MODE == 2) {
          ((float*)outp)[(size_t)grow * N + gcol] =
              resid[(size_t)grow * N + gcol] + val;
        } else if constexpr (MODE == 3) {
          int which = gcol >> 10, hh = (gcol >> 6) & 15, dd = gcol & 63;
          int b = grow >> 10, t = grow & 1023;
          unsigned short hv = f2bf(val);
          size_t bh = (size_t)(b * 16 + hh) << 16;
          if (which == 0)      qo[bh + t * 64 + dd] = hv;
          else if (which == 1) ko[bh + t * 64 + dd] = hv;
          else                 vo[bh + dd * 1024 + t] = hv;
        } else {
          if (gcol < N)
            ((float*)outp)[(size_t)grow * (size_t)N + gcol] = val;
        }
      }
}

// ---------------- 64x64 ring-4 counted-vmcnt NT GEMM (co-resident) ----------
// Tile 64x64: 4 waves 2x2 of 32x32, 4 MFMA/K-tile/wave, 2 loads/thread/tile
// (1 A + 1 B) -> vmcnt ladder 4/2/0. LDS 32 KiB; __launch_bounds__(256,4)
// caps VGPR at 128/wave. For N=1024 GEMMs (aproj/mproj): grid 32x16=512 =
// 2 blocks/CU (was 1 at 128x64) -> co-resident MFMAs hide the counted-vmcnt
// waits (the round-5 mechanism, re-applied).
template <int MODE>
__global__ __launch_bounds__(256, 4) void gemm6464_bt(
    const unsigned short* __restrict__ A, const unsigned short* __restrict__ Wb,
    void* __restrict__ outp, const float* __restrict__ resid, int M, int N,
    int K) {
  __shared__ unsigned short As[4][64 * 32];
  __shared__ unsigned short Bs[4][64 * 32];

  const int tid = threadIdx.x;
  const int lane = tid & 63;
  const int wv = tid >> 6;
  const int lr = lane & 15, lh = lane >> 4;
  const int nbm = M >> 6;
  const int nb = gridDim.x;
  const int bid = blockIdx.x;
  const int swz = (bid & 7) * (nb >> 3) + (bid >> 3);   // bijective XCD chunking
  const int m0 = (swz % nbm) << 6;
  const int n0 = (swz / nbm) << 6;
  const int wm = (wv >> 1) << 5;
  const int wn = (wv & 1) << 5;
  const int nK = K >> 5;

  size_t aoff, boff;
  int ldst;
  {
    int u = tid;                        // 256 lane-loads each (32 phys rows)
    int p = u >> 3, s = u & 7;
    int ss = s ^ (p & 7);
    int arow = m0 + 2 * p + (ss >> 2);
    int brow = n0 + 2 * p + (ss >> 2);
    aoff = (size_t)arow * K + (ss & 3) * 8;
    boff = (size_t)brow * K + (ss & 3) * 8;
    ldst = u * 16;
  }

  auto stage = [&](int buf, int k) {
    gload16(A + aoff + k * 32, (char*)(&As[buf][0]) + ldst);
    gload16(Wb + boff + k * 32, (char*)(&Bs[buf][0]) + ldst);
  };

  f32x4 acc[2][2];
#pragma unroll
  for (int a = 0; a < 2; ++a)
#pragma unroll
    for (int b = 0; b < 2; ++b) acc[a][b] = f32x4{0.f, 0.f, 0.f, 0.f};

  stage(0, 0);
  if (nK > 1) stage(1, 1);
  if (nK > 2) stage(2, 2);
  if (nK > 2)      asm volatile("s_waitcnt vmcnt(4)" ::: "memory");
  else if (nK > 1) asm volatile("s_waitcnt vmcnt(2)" ::: "memory");
  else             asm volatile("s_waitcnt vmcnt(0)" ::: "memory");
  __builtin_amdgcn_s_barrier();
  __builtin_amdgcn_sched_barrier(0);

  for (int kt = 0; kt < nK; ++kt) {
    const int buf = kt & 3;
    bf16x8 af[2], bfr[2];
#pragma unroll
    for (int ni = 0; ni < 2; ++ni) {
      int r = wn + ni * 16 + lr;
      int p = r >> 1;
      int off = p * 128 + (((((r & 1) << 2) | lh) ^ (p & 7)) << 4);
      bfr[ni] = *(const bf16x8*)((const char*)(&Bs[buf][0]) + off);
    }
#pragma unroll
    for (int mi = 0; mi < 2; ++mi) {
      int r = wm + mi * 16 + lr;
      int p = r >> 1;
      int off = p * 128 + (((((r & 1) << 2) | lh) ^ (p & 7)) << 4);
      af[mi] = *(const bf16x8*)((const char*)(&As[buf][0]) + off);
    }
    if (kt + 3 < nK) stage((kt + 3) & 3, kt + 3);

    __builtin_amdgcn_s_setprio(1);
#pragma unroll
    for (int mi = 0; mi < 2; ++mi)
#pragma unroll
      for (int ni = 0; ni < 2; ++ni)
        acc[mi][ni] = __builtin_amdgcn_mfma_f32_16x16x32_bf16(
            af[mi], bfr[ni], acc[mi][ni], 0, 0, 0);
    __builtin_amdgcn_s_setprio(0);

    if (kt + 1 < nK) {
      if (kt + 4 <= nK)      asm volatile("s_waitcnt vmcnt(4)" ::: "memory");
      else if (kt + 3 <= nK) asm volatile("s_waitcnt vmcnt(2)" ::: "memory");
      else                   asm volatile("s_waitcnt vmcnt(0)" ::: "memory");
      __builtin_amdgcn_s_barrier();
      __builtin_amdgcn_sched_barrier(0);
    }
  }

  // epilogue
#pragma unroll
  for (int mi = 0; mi < 2; ++mi)
#pragma unroll
    for (int ni = 0; ni < 2; ++ni)
#pragma unroll
      for (int r = 0; r < 4; ++r) {
        int grow = m0 + wm + mi * 16 + lh * 4 + r;
        int gcol = n0 + wn + ni * 16 + lr;
        float val = acc[mi][ni][r];
        if constexpr (MODE == 1) val = fmaxf(val, 0.f);
        if constexpr (MODE == 0 || MODE == 1) {
          ((unsigned short*)outp)[(size_t)grow * N + gcol] = f2bf(val);
        } else if constexpr (MODE == 2) {
          ((float*)outp)[(size_t)grow * N + gcol] =
              resid[(size_t)grow * N + gcol] + val;
        }
      }
}

// ---------------- 256x256 ring-4 deep-pipelined NT GEMM (head, proven) ------
__global__ __launch_bounds__(512, 2) void gemm256_bt(
    const unsigned short* __restrict__ A, const unsigned short* __restrict__ Wb,
    float* __restrict__ out, int M, int N, int K) {
  __shared__ unsigned short As[4][256 * 32];
  __shared__ unsigned short Bs[4][256 * 32];

  const int tid = threadIdx.x;
  const int lane = tid & 63;
  const int wv = tid >> 6;
  const int lr = lane & 15, lh = lane >> 4;
  const int wm = (wv >> 2) * 128;   // warp_m in {0,1}
  const int wn = (wv & 3) * 64;     // warp_n in {0..3}
  const int nbm = M >> 8;
  const int nb = gridDim.x;
  const int bid = blockIdx.x;
  const int swz = (bid & 7) * (nb >> 3) + (bid >> 3);  // bijective XCD chunking
  const int m0 = (swz % nbm) << 8;
  const int n0 = (swz / nbm) << 8;
  const int nK = K >> 5;

  size_t aoff[2], boff[2];
  int ldst[2];
#pragma unroll
  for (int j = 0; j < 2; ++j) {
    int u = j * 512 + tid;
    int p = u >> 3, s = u & 7;
    int ss = s ^ (p & 7);            // inverse swizzle on the source side
    int arow = m0 + 2 * p + (ss >> 2);
    int brow = n0 + 2 * p + (ss >> 2);
    if (brow >= N) brow = N - 1;
    aoff[j] = (size_t)arow * K + (ss & 3) * 8;
    boff[j] = (size_t)brow * K + (ss & 3) * 8;
    ldst[j] = u * 16;
  }

  auto stage = [&](int buf, int k) {
#pragma unroll
    for (int j = 0; j < 2; ++j)
      gload16(A + aoff[j] + k * 32, (char*)(&As[buf][0]) + ldst[j]);
#pragma unroll
    for (int j = 0; j < 2; ++j)
      gload16(Wb + boff[j] + k * 32, (char*)(&Bs[buf][0]) + ldst[j]);
  };

  f32x4 acc[8][4];
#pragma unroll
  for (int a = 0; a < 8; ++a)
#pragma unroll
    for (int b = 0; b < 4; ++b) acc[a][b] = f32x4{0.f, 0.f, 0.f, 0.f};

  stage(0, 0);
  if (nK > 1) stage(1, 1);
  if (nK > 2) stage(2, 2);
  if (nK > 2) asm volatile("s_waitcnt vmcnt(8)" ::: "memory");
  else        asm volatile("s_waitcnt vmcnt(0)" ::: "memory");
  __builtin_amdgcn_s_barrier();
  __builtin_amdgcn_sched_barrier(0);

  for (int k = 0; k < nK; ++k) {
    const int buf = k & 3;
    bf16x8 af[8], bfr[4];
#pragma unroll
    for (int ni = 0; ni < 4; ++ni) {
      int r = wn + ni * 16 + lr;
      int p = r >> 1;
      int off = p * 128 + (((((r & 1) << 2) | lh) ^ (p & 7)) << 4);
      bfr[ni] = *(const bf16x8*)((const char*)(&Bs[buf][0]) + off);
    }
#pragma unroll
    for (int mi = 0; mi < 8; ++mi) {
      int r = wm + mi * 16 + lr;
      int p = r >> 1;
      int off = p * 128 + (((((r & 1) << 2) | lh) ^ (p & 7)) << 4);
      af[mi] = *(const bf16x8*)((const char*)(&As[buf][0]) + off);
    }
    if (k + 3 < nK) stage((k + 3) & 3, k + 3);

    __builtin_amdgcn_s_setprio(1);
#pragma unroll
    for (int mi = 0; mi < 8; ++mi)
#pragma unroll
      for (int ni = 0; ni < 4; ++ni)
        acc[mi][ni] = __builtin_amdgcn_mfma_f32_16x16x32_bf16(
            af[mi], bfr[ni], acc[mi][ni], 0, 0, 0);
    __builtin_amdgcn_s_setprio(0);

    if (k + 1 < nK) {
      if (k + 4 <= nK)      asm volatile("s_waitcnt vmcnt(8)" ::: "memory");
      else if (k + 3 <= nK) asm volatile("s_waitcnt vmcnt(4)" ::: "memory");
      else                  asm volatile("s_waitcnt vmcnt(0)" ::: "memory");
      __builtin_amdgcn_s_barrier();
      __builtin_amdgcn_sched_barrier(0);
    }
  }

#pragma unroll
  for (int mi = 0; mi < 8; ++mi)
#pragma unroll
    for (int ni = 0; ni < 4; ++ni)
#pragma unroll
      for (int r = 0; r < 4; ++r) {
        int grow = m0 + wm + mi * 16 + lh * 4 + r;
        int gcol = n0 + wn + ni * 16 + lr;
        if (gcol < N) out[(size_t)grow * (size_t)N + gcol] = acc[mi][ni][r];
      }
}

// ---------------- flash attention, causal-balanced, 2 waves/block -------------
__global__ __launch_bounds__(128, 2) void attn_kernel(
    const unsigned short* __restrict__ qb, const unsigned short* __restrict__ kb,
    const unsigned short* __restrict__ vt, unsigned short* __restrict__ yb) {
  __shared__ unsigned short Ks[2][64 * 64];
  __shared__ unsigned short Vs[2][64 * 64];
  __shared__ unsigned short Ps[2][32 * 64];

  const int tid = threadIdx.x, lane = tid & 63, wv = tid >> 6;
  const int lr = lane & 15, lh = lane >> 4;
  const int bid = blockIdx.x;
  const int bh = bid & 31;
  const int rest = bid >> 5;
  const int j = rest >> 1, hf = rest & 1;
  const int sub = (hf * 2 + wv) * 16;
  const int rb0 = j * 64 + sub;              // chunk A rows (mi=0)
  const int rb1 = (15 - j) * 64 + sub;       // chunk B rows (mi=1)
  const unsigned short* qp = qb + ((size_t)bh << 16);
  const unsigned short* kp = kb + ((size_t)bh << 16);
  const unsigned short* vp = vt + ((size_t)bh << 16);

  bf16x8 qf[2][2];
#pragma unroll
  for (int mi = 0; mi < 2; ++mi)
#pragma unroll
    for (int ks = 0; ks < 2; ++ks) {
      int row = (mi ? rb1 : rb0) + lr;
      qf[mi][ks] = *(const bf16x8*)(qp + (size_t)row * 64 + ks * 32 + lh * 8);
    }

  f32x4 o[2][4];
  float mr[2][4], lsum[2][4];
#pragma unroll
  for (int mi = 0; mi < 2; ++mi) {
#pragma unroll
    for (int di = 0; di < 4; ++di) o[mi][di] = f32x4{0.f, 0.f, 0.f, 0.f};
#pragma unroll
    for (int r = 0; r < 4; ++r) { mr[mi][r] = -1e30f; lsum[mi][r] = 0.f; }
  }

  const int ntiles = 16 - j;

  auto stageKV = [&](int buf, int t) {
    int kv0 = t << 6;
#pragma unroll
    for (int jj = 0; jj < 4; ++jj) {
      int u = jj * 128 + tid;
      int row = u >> 3, un = u & 7;
      gload16(kp + (size_t)(kv0 + row) * 64 + ((un ^ (row & 7)) << 3),
              (char*)(&Ks[buf][0]) + u * 16);
      gload16(vp + (size_t)row * 1024 + kv0 + ((un ^ (row & 7)) << 3),
              (char*)(&Vs[buf][0]) + u * 16);
    }
  };

  stageKV(0, 0);

  for (int t = 0; t < ntiles; ++t) {
    __syncthreads();
    if (t + 1 < ntiles) stageKV((t + 1) & 1, t + 1);
    int cur = t & 1;
    int kv0 = t << 6;
    const bool act0 = (t <= j);   // chunk A active this tile (block-uniform)

    f32x4 s[2][4];
#pragma unroll
    for (int mi = 0; mi < 2; ++mi)
#pragma unroll
      for (int ni = 0; ni < 4; ++ni) s[mi][ni] = f32x4{0.f, 0.f, 0.f, 0.f};

    bf16x8 kf[4][2];
#pragma unroll
    for (int ni = 0; ni < 4; ++ni)
#pragma unroll
      for (int ks = 0; ks < 2; ++ks) {
        int row = ni * 16 + lr;
        int off = row * 128 + ((ks * 64 + lh * 16) ^ ((row & 7) << 4));
        kf[ni][ks] = *(const bf16x8*)((const char*)(&Ks[cur][0]) + off);
      }
#pragma unroll
    for (int ks = 0; ks < 2; ++ks)
#pragma unroll
      for (int ni = 0; ni < 4; ++ni) {
        if (act0)
          s[0][ni] = __builtin_amdgcn_mfma_f32_16x16x32_bf16(
              qf[0][ks], kf[ni][ks], s[0][ni], 0, 0, 0);
        s[1][ni] = __builtin_amdgcn_mfma_f32_16x16x32_bf16(
            qf[1][ks], kf[ni][ks], s[1][ni], 0, 0, 0);
      }

    // scale + causal mask + online softmax (per mi; mi=0 gated)
#pragma unroll
    for (int mi = 0; mi < 2; ++mi) {
      if (mi == 0 && !act0) continue;
      const int rb = mi ? rb1 : rb0;
#pragma unroll
      for (int r = 0; r < 4; ++r) {
        int rowq = rb + lh * 4 + r;
        float xv[4];
        float pm = -1e30f;
#pragma unroll
        for (int ni = 0; ni < 4; ++ni) {
          int col = kv0 + ni * 16 + lr;
          float xx = s[mi][ni][r] * 0.125f;
          if (col > rowq) xx = -1e30f;
          xv[ni] = xx;
          pm = fmaxf(pm, xx);
        }
#pragma unroll
        for (int msk = 1; msk < 16; msk <<= 1)
          pm = fmaxf(pm, __shfl_xor(pm, msk, 64));
        float mnew = fmaxf(mr[mi][r], pm);
        float al = exp2f((mr[mi][r] - mnew) * LOG2E);
        mr[mi][r] = mnew;
        float ps = 0.f;
#pragma unroll
        for (int ni = 0; ni < 4; ++ni) {
          float p = exp2f((xv[ni] - mnew) * LOG2E);
          s[mi][ni][r] = p;
          ps += p;
        }
#pragma unroll
        for (int msk = 1; msk < 16; msk <<= 1) ps += __shfl_xor(ps, msk, 64);
        lsum[mi][r] = lsum[mi][r] * al + ps;
#pragma unroll
        for (int di = 0; di < 4; ++di) o[mi][di][r] *= al;
      }
    }

    // P (C-layout) -> per-wave LDS (A-frag layout), swizzled; mi=0 gated
#pragma unroll
    for (int mi = 0; mi < 2; ++mi) {
      if (mi == 0 && !act0) continue;
#pragma unroll
      for (int ni = 0; ni < 4; ++ni)
#pragma unroll
        for (int r = 0; r < 4; ++r) {
          int row = mi * 16 + lh * 4 + r;
          int off = row * 128 + (((ni * 16 + lr) * 2) ^ ((row & 7) << 4));
          *(unsigned short*)((char*)(&Ps[wv][0]) + off) = f2bf(s[mi][ni][r]);
        }
    }

    bf16x8 pf[2][2], vf[4][2];
#pragma unroll
    for (int mi = 0; mi < 2; ++mi) {
      if (mi == 0 && !act0) continue;
#pragma unroll
      for (int ks = 0; ks < 2; ++ks) {
        int row = mi * 16 + lr;
        int off = row * 128 + ((ks * 64 + lh * 16) ^ ((row & 7) << 4));
        pf[mi][ks] = *(const bf16x8*)((const char*)(&Ps[wv][0]) + off);
      }
    }
#pragma unroll
    for (int di = 0; di < 4; ++di)
#pragma unroll
      for (int ks = 0; ks < 2; ++ks) {
        int row = di * 16 + lr;
        int off = row * 128 + ((ks * 64 + lh * 16) ^ ((row & 7) << 4));
        vf[di][ks] = *(const bf16x8*)((const char*)(&Vs[cur][0]) + off);
      }
#pragma unroll
    for (int ks = 0; ks < 2; ++ks)
#pragma unroll
      for (int di = 0; di < 4; ++di) {
        if (act0)
          o[0][di] = __builtin_amdgcn_mfma_f32_16x16x32_bf16(
              pf[0][ks], vf[di][ks], o[0][di], 0, 0, 0);
        o[1][di] = __builtin_amdgcn_mfma_f32_16x16x32_bf16(
            pf[1][ks], vf[di][ks], o[1][di], 0, 0, 0);
      }
  }

  int b = bh >> 4, hh = bh & 15;
#pragma unroll
  for (int mi = 0; mi < 2; ++mi)
#pragma unroll
    for (int r = 0; r < 4; ++r) {
      float inv = 1.f / lsum[mi][r];
      int rowq = (mi ? rb1 : rb0) + lh * 4 + r;
      size_t mg = (size_t)(b * 1024 + rowq) * 1024 + hh * 64;
#pragma unroll
      for (int di = 0; di < 4; ++di)
        yb[mg + di * 16 + lr] = f2bf(o[mi][di][r] * inv);
    }
}

// ---------------- launch ----------------
extern "C" void kernel_launch(void* const* d_in, const int* in_sizes, int n_in,
                              void* d_out, int out_size, void* d_ws,
                              size_t ws_size, hipStream_t stream) {
  const int*   idx  = (const int*)d_in[0];
  const float* wte  = (const float*)d_in[1];
  const float* wpe  = (const float*)d_in[2];
  const float* ln1w = (const float*)d_in[3];
  const float* attnw= (const float*)d_in[4];
  const float* aprj = (const float*)d_in[5];
  const float* ln2w = (const float*)d_in[6];
  const float* fcw  = (const float*)d_in[7];
  const float* mprj = (const float*)d_in[8];
  const float* lnfw = (const float*)d_in[9];
  const float* hw   = (const float*)d_in[10];
  float* out = (float*)d_out;
  char* ws = (char*)d_ws;

  float* x            = (float*)ws;                                  // 8 MB
  unsigned short* h   = (unsigned short*)(ws + ((size_t)8 << 20));   // 4 MB
  unsigned short* qbf = (unsigned short*)(ws + ((size_t)12 << 20));  // 4 MB
  unsigned short* kbf = (unsigned short*)(ws + ((size_t)16 << 20));  // 4 MB
  unsigned short* vtb = (unsigned short*)(ws + ((size_t)20 << 20));  // 4 MB
  unsigned short* ybf = (unsigned short*)(ws + ((size_t)24 << 20));  // 4 MB
  unsigned short* mhb = (unsigned short*)(ws + ((size_t)12 << 20));  // 16 MB, aliases qkv/y (safe by schedule)

  // bf16 weight copies
  size_t off = (size_t)28 << 20;
  unsigned short* attnw16 = (unsigned short*)(ws + off); off += (size_t)4 * 3072 * 1024 * 2;
  unsigned short* aprj16  = (unsigned short*)(ws + off); off += (size_t)4 * 1024 * 1024 * 2;
  unsigned short* fcw16   = (unsigned short*)(ws + off); off += (size_t)4 * 4096 * 1024 * 2;
  unsigned short* mprj16  = (unsigned short*)(ws + off); off += (size_t)4 * 1024 * 4096 * 2;
  unsigned short* hw16    = (unsigned short*)(ws + off); off += (size_t)50257 * 1024 * 2;
  const bool b16 = ws_size >= off;

  embed_kernel<<<2048, 256, 0, stream>>>(idx, wte, wpe, x);

  if (b16) {
    cvt5_kernel<<<2048, 256, 0, stream>>>(
        attnw, attnw16, 4 * 3072 * 1024 / 8,
        aprj,  aprj16,  4 * 1024 * 1024 / 8,
        fcw,   fcw16,   4 * 4096 * 1024 / 8,
        mprj,  mprj16,  4 * 1024 * 4096 / 8,
        hw,    hw16,    50257 * 1024 / 8);
  }

  for (int l = 0; l < 4; ++l) {
    ln_kernel<<<2048, 256, 0, stream>>>(x, ln1w + l * 1024, h);
    if (b16)
      gemm64n_bt<3><<<16 * 48, 256, 0, stream>>>(
          h, attnw16 + (size_t)l * 3072 * 1024, nullptr, nullptr, qbf, kbf,
          vtb, 2048, 3072, 1024);
    else
      gemm_bt<3, false><<<16 * 24, 256, 0, stream>>>(
          h, attnw + (size_t)l * 3072 * 1024, nullptr, nullptr, qbf, kbf, vtb,
          2048, 3072, 1024);
    attn_kernel<<<512, 128, 0, stream>>>(qbf, kbf, vtb, ybf);
    if (b16)
      gemm6464_bt<2><<<32 * 16, 256, 0, stream>>>(
          ybf, aprj16 + (size_t)l * 1024 * 1024, x, x, 2048, 1024, 1024);
    else
      gemm_bt<2, false><<<16 * 8, 256, 0, stream>>>(
          ybf, aprj + (size_t)l * 1024 * 1024, x, x, nullptr, nullptr, nullptr,
          2048, 1024, 1024);
    ln_kernel<<<2048, 256, 0, stream>>>(x, ln2w + l * 1024, h);
    if (b16)
      gemm128_bt<1><<<16 * 32, 256, 0, stream>>>(
          h, fcw16 + (size_t)l * 4096 * 1024, mhb, nullptr, nullptr, nullptr,
          nullptr, 2048, 4096, 1024);
    else
      gemm_bt<1, false><<<16 * 32, 256, 0, stream>>>(
          h, fcw + (size_t)l * 4096 * 1024, mhb, nullptr, nullptr, nullptr,
          nullptr, 2048, 4096, 1024);
    if (b16)
      gemm6464_bt<2><<<32 * 16, 256, 0, stream>>>(
          mhb, mprj16 + (size_t)l * 1024 * 4096, x, x, 2048, 1024, 4096);
    else
      gemm_bt<2, false><<<16 * 8, 256, 0, stream>>>(
          mhb, mprj + (size_t)l * 1024 * 4096, x, x, nullptr, nullptr, nullptr,
          2048, 1024, 4096);
  }

  ln_kernel<<<2048, 256, 0, stream>>>(x, lnfw, h);
  if (b16)
    gemm256_bt<<<8 * 197, 512, 0, stream>>>(h, hw16, out, 2048, 50257, 1024);
  else
    gemm_bt<4, false><<<16 * 393, 256, 0, stream>>>(
        h, hw, out, nullptr, nullptr, nullptr, nullptr, 2048, 50257, 1024);
}